// Round 9
// baseline (3788.934 us; speedup 1.0000x reference)
//
#include <hip/hip_runtime.h>

constexpr int BB = 8, NN = 2048, KK = 20;
constexpr float SLP = 0.2f;
constexpr float NEG = -3.0e38f;
constexpr double EPSD = 1e-5;

typedef short short8 __attribute__((ext_vector_type(8)));
typedef float f32x4 __attribute__((ext_vector_type(4)));
typedef unsigned short ushort;

__device__ __forceinline__ float lrelu(float v) { return v >= 0.f ? v : SLP * v; }

__device__ __forceinline__ float bits2f(unsigned u) { union { unsigned u; float f; } a; a.u = u; return a.f; }
__device__ __forceinline__ unsigned f2bits(float f) { union { float f; unsigned u; } a; a.f = f; return a.u; }

__device__ __forceinline__ ushort bf16rne(float f) {
  unsigned u = f2bits(f);
  return (ushort)((u + 0x7fffu + ((u >> 16) & 1u)) >> 16);
}

__device__ __forceinline__ void split3(float x, ushort& h, ushort& m, ushort& l) {
  h = bf16rne(x);
  float fh = bits2f(((unsigned)h) << 16);
  float t1 = x - fh;
  m = bf16rne(t1);
  float fm = bits2f(((unsigned)m) << 16);
  float t2 = t1 - fm;
  l = bf16rne(t2);
}

// ---------- prep stage 0 ----------
__global__ __launch_bounds__(256) void k_prep0(const float* __restrict__ x, float* __restrict__ x0nc,
                                               ushort* __restrict__ xh, ushort* __restrict__ xm,
                                               ushort* __restrict__ xlo, float* __restrict__ sqb) {
  int i = blockIdx.x * 256 + threadIdx.x;
  if (i >= BB * NN) return;
  int b = i >> 11, n = i & (NN - 1);
  float v[6];
#pragma unroll
  for (int c = 0; c < 6; ++c) v[c] = x[((size_t)b * 6 + c) * NN + n];
  float s = 0.f;
#pragma unroll
  for (int c = 0; c < 6; ++c) s = __fadd_rn(s, __fmul_rn(v[c], v[c]));
  sqb[i] = s;
#pragma unroll
  for (int c = 0; c < 6; ++c) x0nc[(size_t)i * 6 + c] = v[c];
  size_t base = (size_t)i * 32;
#pragma unroll
  for (int c = 0; c < 32; ++c) {
    float xv = (c < 6) ? v[c] : 0.f;
    ushort h, m, l;
    split3(xv, h, m, l);
    xh[base + c] = h; xm[base + c] = m; xlo[base + c] = l;
  }
}

// ---------- fused BN+LReLU apply + split prep ----------
__global__ __launch_bounds__(256) void k_applyprep(float* __restrict__ xio, const double* __restrict__ st,
                                                   const float* __restrict__ g, const float* __restrict__ bb,
                                                   ushort* __restrict__ xh, ushort* __restrict__ xm,
                                                   ushort* __restrict__ xlo, float* __restrict__ sqb) {
  __shared__ float sa[64], sd[64];
  const int tid = threadIdx.x;
  if (tid < 64) {
    constexpr double invM = 1.0 / (double)(BB * NN * KK);
    double sm = st[tid] * invM;
    double ad = (double)g[tid] / sqrt(st[64 + tid] * invM - sm * sm + EPSD);
    sa[tid] = (float)ad;
    sd[tid] = (float)((double)bb[tid] - sm * ad);
  }
  __syncthreads();
  int i = blockIdx.x * 256 + tid;
  float* src = xio + (size_t)i * 64;
  float v[64];
#pragma unroll
  for (int c4 = 0; c4 < 16; ++c4) {
    float4 t = *reinterpret_cast<const float4*>(src + 4 * c4);
    v[4 * c4 + 0] = t.x; v[4 * c4 + 1] = t.y; v[4 * c4 + 2] = t.z; v[4 * c4 + 3] = t.w;
  }
#pragma unroll
  for (int c = 0; c < 64; ++c) v[c] = lrelu(fmaf(sa[c], v[c], sd[c]));
  float s = 0.f;
#pragma unroll
  for (int c = 0; c < 64; ++c) s = __fadd_rn(s, __fmul_rn(v[c], v[c]));
  sqb[i] = s;
#pragma unroll
  for (int c4 = 0; c4 < 16; ++c4) {
    float4 t;
    t.x = v[4 * c4 + 0]; t.y = v[4 * c4 + 1]; t.z = v[4 * c4 + 2]; t.w = v[4 * c4 + 3];
    *reinterpret_cast<float4*>(src + 4 * c4) = t;
  }
  size_t base = (size_t)i * 64;
#pragma unroll
  for (int c = 0; c < 64; ++c) {
    ushort h, m, l;
    split3(v[c], h, m, l);
    xh[base + c] = h; xm[base + c] = m; xlo[base + c] = l;
  }
}

// ---------- FUSED kNN v2: MFMA Gram (bit-identical scores) + per-lane sequential top-20 ----------
// block = 32 rows × 1 batch; 8 chunks of 256 cols; select: wave0 lanes 0-31 own one row each.
template <int CP>
__global__ __launch_bounds__(256) void k_knnf2(const ushort* __restrict__ xh, const ushort* __restrict__ xm,
                                               const ushort* __restrict__ xlo, const float* __restrict__ sqb,
                                               int* __restrict__ idxo) {
  constexpr int KS = CP / 32;
  const int b = blockIdx.y;
  const int r0 = blockIdx.x * 32;
  const int tid = threadIdx.x, w = tid >> 6, l = tid & 63;
  const int rt = w & 1, cg = w >> 1;  // row-half, col-half of this wave
  const size_t xb = (size_t)b * NN * CP;
  const int ko = (l >> 4) * 8;

  __shared__ __align__(16) float sc[32 * 257];
  __shared__ float lv[32][20];
  __shared__ int li[32][20];
  for (int t = tid; t < 32 * 20; t += 256) { lv[t / 20][t % 20] = NEG; li[t / 20][t % 20] = 0; }

  // A fragments: this wave's 16-row half, resident in regs for all chunks
  short8 Ah[KS], Am[KS], Al[KS];
  {
    const int ar = r0 + rt * 16 + (l & 15);
#pragma unroll
    for (int ks = 0; ks < KS; ++ks) {
      size_t o = xb + (size_t)ar * CP + ks * 32 + ko;
      Ah[ks] = *reinterpret_cast<const short8*>(xh + o);
      Am[ks] = *reinterpret_cast<const short8*>(xm + o);
      Al[ks] = *reinterpret_cast<const short8*>(xlo + o);
    }
  }
  float sqi[4];
#pragma unroll
  for (int q = 0; q < 4; ++q) sqi[q] = sqb[b * NN + r0 + rt * 16 + (l >> 4) * 4 + q];

  float thr = NEG;          // per-select-lane cached 20th value
  const int srow = l;       // wave0, lanes 0-31 only

  for (int chunk = 0; chunk < 8; ++chunk) {
    // ---- compute phase: wave covers col-tiles chunk*16 + cg*8 + [0,8) ----
    int ct = chunk * 16 + cg * 8;
    short8 Bh[KS], Bm[KS], Bl[KS], Ch[KS], Cm[KS], Cl[KS];
#pragma unroll
    for (int ks = 0; ks < KS; ++ks) {
      size_t o = xb + (size_t)(ct * 16 + (l & 15)) * CP + ks * 32 + ko;
      Bh[ks] = *reinterpret_cast<const short8*>(xh + o);
      Bm[ks] = *reinterpret_cast<const short8*>(xm + o);
      Bl[ks] = *reinterpret_cast<const short8*>(xlo + o);
    }
    for (int t8 = 0; t8 < 8; ++t8) {
      if (t8 < 7) {
#pragma unroll
        for (int ks = 0; ks < KS; ++ks) {
          size_t o = xb + (size_t)((ct + 1) * 16 + (l & 15)) * CP + ks * 32 + ko;
          Ch[ks] = *reinterpret_cast<const short8*>(xh + o);
          Cm[ks] = *reinterpret_cast<const short8*>(xm + o);
          Cl[ks] = *reinterpret_cast<const short8*>(xlo + o);
        }
      }
      f32x4 acc = {0.f, 0.f, 0.f, 0.f};
#pragma unroll
      for (int ks = 0; ks < KS; ++ks) {
        acc = __builtin_amdgcn_mfma_f32_16x16x32_bf16(Am[ks], Bm[ks], acc, 0, 0, 0);
        acc = __builtin_amdgcn_mfma_f32_16x16x32_bf16(Ah[ks], Bl[ks], acc, 0, 0, 0);
        acc = __builtin_amdgcn_mfma_f32_16x16x32_bf16(Al[ks], Bh[ks], acc, 0, 0, 0);
        acc = __builtin_amdgcn_mfma_f32_16x16x32_bf16(Ah[ks], Bm[ks], acc, 0, 0, 0);
        acc = __builtin_amdgcn_mfma_f32_16x16x32_bf16(Am[ks], Bh[ks], acc, 0, 0, 0);
        acc = __builtin_amdgcn_mfma_f32_16x16x32_bf16(Ah[ks], Bh[ks], acc, 0, 0, 0);
      }
      int col = ct * 16 + (l & 15);
      float sqj = sqb[b * NN + col];
      int lcol = col - chunk * 256;
#pragma unroll
      for (int q = 0; q < 4; ++q) {
        float s = __fsub_rn(__fsub_rn(2.f * acc[q], sqi[q]), sqj);
        sc[(rt * 16 + (l >> 4) * 4 + q) * 257 + lcol] = s;
      }
#pragma unroll
      for (int ks = 0; ks < KS; ++ks) { Bh[ks] = Ch[ks]; Bm[ks] = Cm[ks]; Bl[ks] = Cl[ks]; }
      ++ct;
    }
    __syncthreads();
    // ---- select phase: wave0 lanes 0-31, one row each, sequential exact insertion ----
    if (w == 0 && l < 32) {
      const float* rowp = sc + srow * 257;
      const int jb = chunk * 256;
#pragma unroll 4
      for (int c = 0; c < 256; ++c) {
        float v = rowp[c];
        if (v > thr) {   // strict: value-ties keep earlier (lower) index — matches top_k
          int p = 19;
          while (p > 0 && lv[srow][p - 1] < v) {
            lv[srow][p] = lv[srow][p - 1];
            li[srow][p] = li[srow][p - 1];
            --p;
          }
          lv[srow][p] = v;
          li[srow][p] = jb + c;
          thr = lv[srow][19];
        }
      }
    }
    __syncthreads();
  }
  if (w == 0 && l < 32) {
#pragma unroll
    for (int p = 0; p < KK; ++p)
      idxo[((size_t)b * NN + r0 + srow) * KK + p] = li[srow][p];
  }
}

// ---------- u = (W1-W2)x, v = W2 x ----------
template <int C>
__global__ __launch_bounds__(256) void k_uv(const float* __restrict__ xin, const float* __restrict__ w,
                                            float* __restrict__ u, float* __restrict__ v) {
  const int b = blockIdx.y, n0 = blockIdx.x * 4;
  const int tid = threadIdx.x, o = tid & 63, nn = tid >> 6;
  __shared__ float wl[64][2 * C + 1];
  __shared__ float xl[4][C];
  for (int t = tid; t < 64 * 2 * C; t += 256) wl[t / (2 * C)][t % (2 * C)] = w[t];
  for (int t = tid; t < 4 * C; t += 256) xl[t / C][t % C] = xin[((size_t)b * NN + n0 + t / C) * C + t % C];
  __syncthreads();
  float s1 = 0.f, s2 = 0.f;
#pragma unroll
  for (int c = 0; c < C; ++c) {
    float xv = xl[nn][c];
    s1 = fmaf(wl[o][c], xv, s1);
    s2 = fmaf(wl[o][C + c], xv, s2);
  }
  size_t i = ((size_t)b * NN + n0 + nn) * 64 + o;
  u[i] = s1 - s2;
  v[i] = s2;
}

// ---------- stats of t1 = u[n] + v[j] ----------
__global__ __launch_bounds__(256) void k_passA(const float* __restrict__ u, const float* __restrict__ v,
                                               const int* __restrict__ idx, double* __restrict__ st) {
  const int b = blockIdx.y, n0 = blockIdx.x * 16;
  const int tid = threadIdx.x, c = tid & 63, nw = tid >> 6;
  double s = 0.0, ss = 0.0;
  for (int nn = nw; nn < 16; nn += 4) {
    size_t nb = (size_t)b * NN + n0 + nn;
    float uu = u[nb * 64 + c];
    const int* ip = idx + nb * KK;
#pragma unroll
    for (int k = 0; k < KK; ++k) {
      float val = uu + v[((size_t)b * NN + ip[k]) * 64 + c];
      double dv = (double)val;
      s += dv; ss = fma(dv, dv, ss);
    }
  }
  __shared__ double red[2][4][64];
  red[0][nw][c] = s; red[1][nw][c] = ss;
  __syncthreads();
  if (tid < 64) {
    double S = red[0][0][tid] + red[0][1][tid] + red[0][2][tid] + red[0][3][tid];
    double SS = red[1][0][tid] + red[1][1][tid] + red[1][2][tid] + red[1][3][tid];
    atomicAdd(&st[tid], S);
    atomicAdd(&st[64 + tid], SS);
  }
}

// ---------- single-stage: stats + max over k ----------
__global__ __launch_bounds__(256) void k_passAmax(const float* __restrict__ u, const float* __restrict__ v,
                                                  const int* __restrict__ idx, float* __restrict__ xout,
                                                  double* __restrict__ st) {
  const int b = blockIdx.y, n0 = blockIdx.x * 16;
  const int tid = threadIdx.x, c = tid & 63, nw = tid >> 6;
  double s = 0.0, ss = 0.0;
  for (int nn = nw; nn < 16; nn += 4) {
    size_t nb = (size_t)b * NN + n0 + nn;
    float uu = u[nb * 64 + c];
    const int* ip = idx + nb * KK;
    float mx = NEG;
#pragma unroll
    for (int k = 0; k < KK; ++k) {
      float val = uu + v[((size_t)b * NN + ip[k]) * 64 + c];
      mx = fmaxf(mx, val);
      double dv = (double)val;
      s += dv; ss = fma(dv, dv, ss);
    }
    xout[nb * 64 + c] = mx;
  }
  __shared__ double red[2][4][64];
  red[0][nw][c] = s; red[1][nw][c] = ss;
  __syncthreads();
  if (tid < 64) {
    double S = red[0][0][tid] + red[0][1][tid] + red[0][2][tid] + red[0][3][tid];
    double SS = red[1][0][tid] + red[1][1][tid] + red[1][2][tid] + red[1][3][tid];
    atomicAdd(&st[tid], S);
    atomicAdd(&st[64 + tid], SS);
  }
}

// ---------- multi-stage conv2 (r5 variant verbatim: 110 µs, bit-exact) ----------
__global__ __launch_bounds__(256) void k_passB(const float* __restrict__ u, const float* __restrict__ v,
                                               const int* __restrict__ idx, const double* __restrict__ st1,
                                               const float* __restrict__ g1, const float* __restrict__ b1,
                                               const float* __restrict__ w2, float* __restrict__ xout,
                                               double* __restrict__ st2) {
  const int b = blockIdx.y, n0 = blockIdx.x * 8;
  const int tid = threadIdx.x, lane = tid & 63, wv = tid >> 6;
  __shared__ __align__(16) float act[160][64];
  constexpr double invM = 1.0 / (double)(BB * NN * KK);
  double sm = st1[lane] * invM;
  double ad = (double)g1[lane] / sqrt(st1[64 + lane] * invM - sm * sm + EPSD);
  float a = (float)ad;
  float d = (float)((double)b1[lane] - sm * ad);
  float wr[64];
#pragma unroll
  for (int c4 = 0; c4 < 16; ++c4) {
    float4 t4 = *reinterpret_cast<const float4*>(w2 + (size_t)lane * 64 + 4 * c4);
    wr[4 * c4 + 0] = t4.x; wr[4 * c4 + 1] = t4.y; wr[4 * c4 + 2] = t4.z; wr[4 * c4 + 3] = t4.w;
  }
  for (int p = wv; p < 160; p += 4) {
    int nn = p / 20, k = p - nn * 20;
    size_t nb = (size_t)b * NN + n0 + nn;
    int j = idx[nb * KK + k];
    float val = u[nb * 64 + lane] + v[((size_t)b * NN + j) * 64 + lane];
    act[p][lane] = lrelu(fmaf(a, val, d));
  }
  __syncthreads();
  double s2 = 0.0, ss2 = 0.0;
#pragma unroll
  for (int q = 0; q < 2; ++q) {
    int nl = 2 * wv + q;
    float mx = NEG;
#pragma unroll 4
    for (int k = 0; k < KK; ++k) {
      const float* ap = &act[nl * 20 + k][0];
      float a0 = 0.f, a1 = 0.f, a2 = 0.f, a3 = 0.f;
#pragma unroll
      for (int c4 = 0; c4 < 16; ++c4) {
        float4 v4 = *reinterpret_cast<const float4*>(ap + 4 * c4);
        a0 = fmaf(wr[4 * c4 + 0], v4.x, a0);
        a1 = fmaf(wr[4 * c4 + 1], v4.y, a1);
        a2 = fmaf(wr[4 * c4 + 2], v4.z, a2);
        a3 = fmaf(wr[4 * c4 + 3], v4.w, a3);
      }
      float t2v = (a0 + a1) + (a2 + a3);
      mx = fmaxf(mx, t2v);
      double dv = (double)t2v;
      s2 += dv; ss2 = fma(dv, dv, ss2);
    }
    xout[((size_t)b * NN + n0 + nl) * 64 + lane] = mx;
  }
  __syncthreads();
  double* red = reinterpret_cast<double*>(&act[0][0]);
  red[wv * 64 + lane] = s2;
  red[256 + wv * 64 + lane] = ss2;
  __syncthreads();
  if (tid < 64) {
    double S = red[tid] + red[64 + tid] + red[128 + tid] + red[192 + tid];
    double SS = red[256 + tid] + red[320 + tid] + red[384 + tid] + red[448 + tid];
    atomicAdd(&st2[tid], S);
    atomicAdd(&st2[64 + tid], SS);
  }
}

// ---------- in-place BN+LReLU (stage 3 output) ----------
__global__ __launch_bounds__(256) void k_apply(float* __restrict__ xio, const double* __restrict__ st,
                                               const float* __restrict__ g, const float* __restrict__ bb,
                                               double invM) {
  const int b = blockIdx.y, n0 = blockIdx.x * 4;
  const int tid = threadIdx.x, c = tid & 63, nn = tid >> 6;
  double sm = st[c] * invM;
  double ad = (double)g[c] / sqrt(st[64 + c] * invM - sm * sm + EPSD);
  float a = (float)ad;
  float d = (float)((double)bb[c] - sm * ad);
  size_t i = ((size_t)b * NN + n0 + nn) * 64 + c;
  xio[i] = lrelu(fmaf(a, xio[i], d));
}

// ---------- wt transpose ----------
__global__ __launch_bounds__(256) void k_wtT(const float* __restrict__ wt, float* __restrict__ wtT) {
  int i = blockIdx.x * 256 + threadIdx.x;
  if (i < 128 * 256) { int o = i >> 8, c = i & 255; wtT[c * 128 + o] = wt[i]; }
}

// ---------- tail GEMM ----------
__global__ __launch_bounds__(256) void k_tail(const float* __restrict__ x1, const float* __restrict__ x2,
                                              const float* __restrict__ x3, const float* __restrict__ x4,
                                              const float* __restrict__ wtT, float* __restrict__ tt) {
  const int b = blockIdx.y, n0 = blockIdx.x * 16;
  const int tid = threadIdx.x, og = tid & 31, nt = tid >> 5;
  __shared__ float xc[256][20];
  const float* xs[4] = {x1, x2, x3, x4};
  for (int t = tid; t < 4096; t += 256) {
    int n = t >> 8, c = t & 255;
    xc[c][n] = xs[c >> 6][((size_t)b * NN + n0 + n) * 64 + (c & 63)];
  }
  __syncthreads();
  float acc[4][2];
#pragma unroll
  for (int r = 0; r < 4; ++r) { acc[r][0] = 0.f; acc[r][1] = 0.f; }
#pragma unroll 4
  for (int c = 0; c < 256; ++c) {
    float4 wv = *reinterpret_cast<const float4*>(&wtT[(size_t)c * 128 + 4 * og]);
    float xc0 = xc[c][2 * nt], xc1 = xc[c][2 * nt + 1];
    acc[0][0] = fmaf(wv.x, xc0, acc[0][0]); acc[0][1] = fmaf(wv.x, xc1, acc[0][1]);
    acc[1][0] = fmaf(wv.y, xc0, acc[1][0]); acc[1][1] = fmaf(wv.y, xc1, acc[1][1]);
    acc[2][0] = fmaf(wv.z, xc0, acc[2][0]); acc[2][1] = fmaf(wv.z, xc1, acc[2][1]);
    acc[3][0] = fmaf(wv.w, xc0, acc[3][0]); acc[3][1] = fmaf(wv.w, xc1, acc[3][1]);
  }
#pragma unroll
  for (int q = 0; q < 2; ++q) {
    float4 o4;
    o4.x = acc[0][q]; o4.y = acc[1][q]; o4.z = acc[2][q]; o4.w = acc[3][q];
    *reinterpret_cast<float4*>(&tt[((size_t)b * NN + n0 + 2 * nt + q) * 128 + 4 * og]) = o4;
  }
}

// ---------- tail stats ----------
__global__ __launch_bounds__(256) void k_tailstats(const float* __restrict__ tt, double* __restrict__ st) {
  const int tid = threadIdx.x, c = tid & 127, h = tid >> 7;
  const int r0 = blockIdx.x * 32;
  double s = 0.0, ss = 0.0;
  for (int rr = h; rr < 32; rr += 2) {
    double val = (double)tt[(size_t)(r0 + rr) * 128 + c];
    s += val; ss = fma(val, val, ss);
  }
  __shared__ double red[2][2][128];
  red[0][h][c] = s; red[1][h][c] = ss;
  __syncthreads();
  if (tid < 128) {
    atomicAdd(&st[tid], red[0][0][tid] + red[0][1][tid]);
    atomicAdd(&st[128 + tid], red[1][0][tid] + red[1][1][tid]);
  }
}

// ---------- tail BN+LReLU + transpose ----------
__global__ __launch_bounds__(256) void k_tailapply(const float* __restrict__ tt, const double* __restrict__ st,
                                                   const float* __restrict__ g, const float* __restrict__ bb,
                                                   float* __restrict__ out) {
  const int b = blockIdx.y, n0 = blockIdx.x * 64;
  const int tid = threadIdx.x;
  __shared__ float tl[128][65];
  constexpr double invM = 1.0 / (double)(BB * NN);
  {
    const int o = tid & 127, h = tid >> 7;
    double sm = st[o] * invM;
    double ad = (double)g[o] / sqrt(st[128 + o] * invM - sm * sm + EPSD);
    float a = (float)ad;
    float d = (float)((double)bb[o] - sm * ad);
    for (int nn2 = h; nn2 < 64; nn2 += 2) {
      float val = tt[((size_t)b * NN + n0 + nn2) * 128 + o];
      tl[o][nn2] = lrelu(fmaf(a, val, d));
    }
  }
  __syncthreads();
  {
    const int nl = tid & 63, ow = tid >> 6;
    for (int o = ow; o < 128; o += 4)
      out[((size_t)b * 128 + o) * NN + n0 + nl] = tl[o][nl];
  }
}

extern "C" void kernel_launch(void* const* d_in, const int* in_sizes, int n_in,
                              void* d_out, int out_size, void* d_ws, size_t ws_size,
                              hipStream_t stream) {
  const float* x = (const float*)d_in[0];
  const float* w0a = (const float*)d_in[1];
  const float* g0a = (const float*)d_in[2];
  const float* b0a = (const float*)d_in[3];
  const float* w0b = (const float*)d_in[4];
  const float* g0b = (const float*)d_in[5];
  const float* b0b = (const float*)d_in[6];
  const float* w1a = (const float*)d_in[7];
  const float* g1a = (const float*)d_in[8];
  const float* b1a = (const float*)d_in[9];
  const float* w1b = (const float*)d_in[10];
  const float* g1b = (const float*)d_in[11];
  const float* b1b = (const float*)d_in[12];
  const float* w2 = (const float*)d_in[13];
  const float* g2 = (const float*)d_in[14];
  const float* b2 = (const float*)d_in[15];
  const float* w3 = (const float*)d_in[16];
  const float* g3 = (const float*)d_in[17];
  const float* b3 = (const float*)d_in[18];
  const float* wt = (const float*)d_in[19];
  const float* gt = (const float*)d_in[20];
  const float* bt = (const float*)d_in[21];
  float* out = (float*)d_out;

  char* p = (char*)d_ws;
  double* stA = (double*)p; p += 2048;
  double* stB = (double*)p; p += 2048;
  double* stT = (double*)p; p += 2048;
  ushort* xh = (ushort*)p; p += (size_t)BB * NN * 64 * 2;
  ushort* xm = (ushort*)p; p += (size_t)BB * NN * 64 * 2;
  ushort* xlo = (ushort*)p; p += (size_t)BB * NN * 64 * 2;
  float* sqb = (float*)p; p += (size_t)BB * NN * 4;
  float* x0nc = (float*)p; p += (size_t)BB * NN * 6 * 4;
  float* x1 = (float*)p; p += (size_t)BB * NN * 64 * 4;
  float* x2 = (float*)p; p += (size_t)BB * NN * 64 * 4;
  float* x3 = (float*)p; p += (size_t)BB * NN * 64 * 4;
  float* x4 = (float*)p; p += (size_t)BB * NN * 64 * 4;
  float* ub = (float*)p; p += (size_t)BB * NN * 64 * 4;
  float* vb = (float*)p; p += (size_t)BB * NN * 64 * 4;
  float* ttl = (float*)p; p += (size_t)BB * NN * 128 * 4;
  float* wtTb = (float*)p; p += 128 * 256 * 4;
  int* idx = (int*)p; p += (size_t)BB * NN * KK * 4;

  constexpr double invMe = 1.0 / (double)(BB * NN * KK);
  dim3 blk(256);
  dim3 kgrid(NN / 32, BB);

  // stage 0 (multi, C=6)
  k_prep0<<<dim3(BB * NN / 256), blk, 0, stream>>>(x, x0nc, xh, xm, xlo, sqb);
  k_knnf2<32><<<kgrid, blk, 0, stream>>>(xh, xm, xlo, sqb, idx);
  k_uv<6><<<dim3(NN / 4, BB), blk, 0, stream>>>(x0nc, w0a, ub, vb);
  hipMemsetAsync(stA, 0, 4096, stream);  // stA+stB contiguous
  k_passA<<<dim3(NN / 16, BB), blk, 0, stream>>>(ub, vb, idx, stA);
  k_passB<<<dim3(NN / 8, BB), blk, 0, stream>>>(ub, vb, idx, stA, g0a, b0a, w0b, x1, stB);
  k_applyprep<<<dim3(BB * NN / 256), blk, 0, stream>>>(x1, stB, g0b, b0b, xh, xm, xlo, sqb);

  // stage 1 (multi, C=64)
  k_knnf2<64><<<kgrid, blk, 0, stream>>>(xh, xm, xlo, sqb, idx);
  k_uv<64><<<dim3(NN / 4, BB), blk, 0, stream>>>(x1, w1a, ub, vb);
  hipMemsetAsync(stA, 0, 4096, stream);
  k_passA<<<dim3(NN / 16, BB), blk, 0, stream>>>(ub, vb, idx, stA);
  k_passB<<<dim3(NN / 8, BB), blk, 0, stream>>>(ub, vb, idx, stA, g1a, b1a, w1b, x2, stB);
  k_applyprep<<<dim3(BB * NN / 256), blk, 0, stream>>>(x2, stB, g1b, b1b, xh, xm, xlo, sqb);

  // stage 2 (single)
  k_knnf2<64><<<kgrid, blk, 0, stream>>>(xh, xm, xlo, sqb, idx);
  k_uv<64><<<dim3(NN / 4, BB), blk, 0, stream>>>(x2, w2, ub, vb);
  hipMemsetAsync(stA, 0, 2048, stream);
  k_passAmax<<<dim3(NN / 16, BB), blk, 0, stream>>>(ub, vb, idx, x3, stA);
  k_applyprep<<<dim3(BB * NN / 256), blk, 0, stream>>>(x3, stA, g2, b2, xh, xm, xlo, sqb);

  // stage 3 (single)
  k_knnf2<64><<<kgrid, blk, 0, stream>>>(xh, xm, xlo, sqb, idx);
  k_uv<64><<<dim3(NN / 4, BB), blk, 0, stream>>>(x3, w3, ub, vb);
  hipMemsetAsync(stA, 0, 2048, stream);
  k_passAmax<<<dim3(NN / 16, BB), blk, 0, stream>>>(ub, vb, idx, x4, stA);
  k_apply<<<dim3(NN / 4, BB), blk, 0, stream>>>(x4, stA, g3, b3, invMe);

  // tail
  k_wtT<<<dim3(128), blk, 0, stream>>>(wt, wtTb);
  k_tail<<<dim3(NN / 16, BB), blk, 0, stream>>>(x1, x2, x3, x4, wtTb, ttl);
  hipMemsetAsync(stT, 0, 2048, stream);
  k_tailstats<<<dim3(512), blk, 0, stream>>>(ttl, stT);
  k_tailapply<<<dim3(NN / 64, BB), blk, 0, stream>>>(ttl, stT, gt, bt, out);
}

// Round 10
// 1576.341 us; speedup vs baseline: 2.4036x; 2.4036x over previous
//
#include <hip/hip_runtime.h>

constexpr int BB = 8, NN = 2048, KK = 20;
constexpr float SLP = 0.2f;
constexpr float NEG = -3.0e38f;    // extracted-mark
constexpr float EMPTYV = -3.3e38f; // cache-empty sentinel
constexpr double EPSD = 1e-5;

typedef short short8 __attribute__((ext_vector_type(8)));
typedef float f32x4 __attribute__((ext_vector_type(4)));
typedef unsigned short ushort;

__device__ __forceinline__ float lrelu(float v) { return v >= 0.f ? v : SLP * v; }

__device__ __forceinline__ float bits2f(unsigned u) { union { unsigned u; float f; } a; a.u = u; return a.f; }
__device__ __forceinline__ unsigned f2bits(float f) { union { float f; unsigned u; } a; a.f = f; return a.u; }

__device__ __forceinline__ ushort bf16rne(float f) {
  unsigned u = f2bits(f);
  return (ushort)((u + 0x7fffu + ((u >> 16) & 1u)) >> 16);
}

__device__ __forceinline__ void split3(float x, ushort& h, ushort& m, ushort& l) {
  h = bf16rne(x);
  float fh = bits2f(((unsigned)h) << 16);
  float t1 = x - fh;
  m = bf16rne(t1);
  float fm = bits2f(((unsigned)m) << 16);
  float t2 = t1 - fm;
  l = bf16rne(t2);
}

// ---------- prep stage 0 ----------
__global__ __launch_bounds__(256) void k_prep0(const float* __restrict__ x, float* __restrict__ x0nc,
                                               ushort* __restrict__ xh, ushort* __restrict__ xm,
                                               ushort* __restrict__ xlo, float* __restrict__ sqb) {
  int i = blockIdx.x * 256 + threadIdx.x;
  if (i >= BB * NN) return;
  int b = i >> 11, n = i & (NN - 1);
  float v[6];
#pragma unroll
  for (int c = 0; c < 6; ++c) v[c] = x[((size_t)b * 6 + c) * NN + n];
  float s = 0.f;
#pragma unroll
  for (int c = 0; c < 6; ++c) s = __fadd_rn(s, __fmul_rn(v[c], v[c]));
  sqb[i] = s;
#pragma unroll
  for (int c = 0; c < 6; ++c) x0nc[(size_t)i * 6 + c] = v[c];
  size_t base = (size_t)i * 32;
#pragma unroll
  for (int c = 0; c < 32; ++c) {
    float xv = (c < 6) ? v[c] : 0.f;
    ushort h, m, l;
    split3(xv, h, m, l);
    xh[base + c] = h; xm[base + c] = m; xlo[base + c] = l;
  }
}

// ---------- fused BN+LReLU apply + split prep ----------
__global__ __launch_bounds__(256) void k_applyprep(float* __restrict__ xio, const double* __restrict__ st,
                                                   const float* __restrict__ g, const float* __restrict__ bb,
                                                   ushort* __restrict__ xh, ushort* __restrict__ xm,
                                                   ushort* __restrict__ xlo, float* __restrict__ sqb) {
  __shared__ float sa[64], sd[64];
  const int tid = threadIdx.x;
  if (tid < 64) {
    constexpr double invM = 1.0 / (double)(BB * NN * KK);
    double sm = st[tid] * invM;
    double ad = (double)g[tid] / sqrt(st[64 + tid] * invM - sm * sm + EPSD);
    sa[tid] = (float)ad;
    sd[tid] = (float)((double)bb[tid] - sm * ad);
  }
  __syncthreads();
  int i = blockIdx.x * 256 + tid;
  float* src = xio + (size_t)i * 64;
  float v[64];
#pragma unroll
  for (int c4 = 0; c4 < 16; ++c4) {
    float4 t = *reinterpret_cast<const float4*>(src + 4 * c4);
    v[4 * c4 + 0] = t.x; v[4 * c4 + 1] = t.y; v[4 * c4 + 2] = t.z; v[4 * c4 + 3] = t.w;
  }
#pragma unroll
  for (int c = 0; c < 64; ++c) v[c] = lrelu(fmaf(sa[c], v[c], sd[c]));
  float s = 0.f;
#pragma unroll
  for (int c = 0; c < 64; ++c) s = __fadd_rn(s, __fmul_rn(v[c], v[c]));
  sqb[i] = s;
#pragma unroll
  for (int c4 = 0; c4 < 16; ++c4) {
    float4 t;
    t.x = v[4 * c4 + 0]; t.y = v[4 * c4 + 1]; t.z = v[4 * c4 + 2]; t.w = v[4 * c4 + 3];
    *reinterpret_cast<float4*>(src + 4 * c4) = t;
  }
  size_t base = (size_t)i * 64;
#pragma unroll
  for (int c = 0; c < 64; ++c) {
    ushort h, m, l;
    split3(v[c], h, m, l);
    xh[base + c] = h; xm[base + c] = m; xlo[base + c] = l;
  }
}

// ---------- FUSED kNN v3: r8's MFMA compute + r5's extraction select (both proven) ----------
// block = 16 rows × 1 batch; scores for all 2048 cols in LDS sc[16][2052] (swizzled chunks);
// wave w computes col-tiles [w*32,(w+1)*32), then selects rows w*4..w*4+3 via r5 algorithm.
template <int CP>
__global__ __launch_bounds__(256) void k_knnf3(const ushort* __restrict__ xh, const ushort* __restrict__ xm,
                                               const ushort* __restrict__ xlo, const float* __restrict__ sqb,
                                               int* __restrict__ idxo) {
  constexpr int KS = CP / 32;
  constexpr int RS = 2052;  // row stride (floats): +4 pad -> 2-way (free) write conflicts
  const int blk = blockIdx.x;
  const int b = blk & 7;            // consecutive dispatch idx -> different batch -> XCD affinity
  const int r0 = (blk >> 3) * 16;
  const int tid = threadIdx.x, w = tid >> 6, l = tid & 63;
  const size_t xb = (size_t)b * NN * CP;
  const int ko = (l >> 4) * 8;

  __shared__ __align__(16) float sc[16 * RS];
  __shared__ int oid[16][20];

  // A fragments: the block's 16 rows, shared by all waves
  short8 Ah[KS], Am[KS], Al[KS];
  {
    const int ar = r0 + (l & 15);
#pragma unroll
    for (int ks = 0; ks < KS; ++ks) {
      size_t o = xb + (size_t)ar * CP + ks * 32 + ko;
      Ah[ks] = *reinterpret_cast<const short8*>(xh + o);
      Am[ks] = *reinterpret_cast<const short8*>(xm + o);
      Al[ks] = *reinterpret_cast<const short8*>(xlo + o);
    }
  }
  float sqi[4];
#pragma unroll
  for (int q = 0; q < 4; ++q) sqi[q] = sqb[b * NN + r0 + (l >> 4) * 4 + q];

  // ---- compute phase (r8-proven numerics, bit-identical scores) ----
  int ct = w * 32;
  short8 Bh[KS], Bm[KS], Bl[KS], Ch[KS], Cm[KS], Cl[KS];
#pragma unroll
  for (int ks = 0; ks < KS; ++ks) {
    size_t o = xb + (size_t)(ct * 16 + (l & 15)) * CP + ks * 32 + ko;
    Bh[ks] = *reinterpret_cast<const short8*>(xh + o);
    Bm[ks] = *reinterpret_cast<const short8*>(xm + o);
    Bl[ks] = *reinterpret_cast<const short8*>(xlo + o);
  }
  for (int t = 0; t < 32; ++t) {
    if (t < 31) {
#pragma unroll
      for (int ks = 0; ks < KS; ++ks) {
        size_t o = xb + (size_t)((ct + 1) * 16 + (l & 15)) * CP + ks * 32 + ko;
        Ch[ks] = *reinterpret_cast<const short8*>(xh + o);
        Cm[ks] = *reinterpret_cast<const short8*>(xm + o);
        Cl[ks] = *reinterpret_cast<const short8*>(xlo + o);
      }
    }
    f32x4 acc = {0.f, 0.f, 0.f, 0.f};
#pragma unroll
    for (int ks = 0; ks < KS; ++ks) {
      acc = __builtin_amdgcn_mfma_f32_16x16x32_bf16(Am[ks], Bm[ks], acc, 0, 0, 0);
      acc = __builtin_amdgcn_mfma_f32_16x16x32_bf16(Ah[ks], Bl[ks], acc, 0, 0, 0);
      acc = __builtin_amdgcn_mfma_f32_16x16x32_bf16(Al[ks], Bh[ks], acc, 0, 0, 0);
      acc = __builtin_amdgcn_mfma_f32_16x16x32_bf16(Ah[ks], Bm[ks], acc, 0, 0, 0);
      acc = __builtin_amdgcn_mfma_f32_16x16x32_bf16(Am[ks], Bh[ks], acc, 0, 0, 0);
      acc = __builtin_amdgcn_mfma_f32_16x16x32_bf16(Ah[ks], Bh[ks], acc, 0, 0, 0);
    }
    int col = ct * 16 + (l & 15);
    float sqj = sqb[b * NN + col];
    int chunk = col >> 2;
    int cs = chunk ^ ((chunk >> 3) & 7);
#pragma unroll
    for (int q = 0; q < 4; ++q) {
      float s = __fsub_rn(__fsub_rn(2.f * acc[q], sqi[q]), sqj);
      sc[((l >> 4) * 4 + q) * RS + cs * 4 + (col & 3)] = s;
    }
#pragma unroll
    for (int ks = 0; ks < KS; ++ks) { Bh[ks] = Ch[ks]; Bm[ks] = Cm[ks]; Bl[ks] = Cl[ks]; }
    ++ct;
  }
  __syncthreads();

  // ---- select phase: r5 k_select verbatim, one wave per row, 4 rows per wave ----
  for (int rr = 0; rr < 4; ++rr) {
    const int row = w * 4 + rr;
    char* base = reinterpret_cast<char*>(&sc[row * RS]);
    float v0 = EMPTYV, v1 = EMPTYV;
    int i0 = -1, i1 = -1;
#pragma unroll
    for (int e = 0; e < 8; ++e) {
      int c = l * 8 + e;
      c ^= (c >> 3) & 7;
      float4 v = *reinterpret_cast<const float4*>(base + (c << 4));
      int jb = l * 32 + e * 4;
      float va[4] = {v.x, v.y, v.z, v.w};
#pragma unroll
      for (int q = 0; q < 4; ++q) {
        float vv = va[q];
        int jj = jb + q;
        if (vv > v0) { v1 = v0; i1 = i0; v0 = vv; i0 = jj; }
        else if (vv > v1) { v1 = vv; i1 = jj; }
      }
    }
    for (int e = 0; e < KK; ++e) {
      float m = v0;
#pragma unroll
      for (int d = 1; d < 64; d <<= 1) m = fmaxf(m, __shfl_xor(m, d));
      unsigned long long msk = __ballot(v0 == m);
      int wl = __ffsll((unsigned long long)msk) - 1;
      if (l == wl) {
        oid[row][e] = i0;
        int j = i0;
        int cc = j >> 2;
        int cs2 = cc ^ ((cc >> 3) & 7);
        *reinterpret_cast<float*>(base + (cs2 << 4) + ((j & 3) << 2)) = NEG;
        v0 = v1; i0 = i1; v1 = EMPTYV; i1 = -1;
        if (v0 <= EMPTYV) {
          v0 = EMPTYV; v1 = EMPTYV; i0 = -1; i1 = -1;
#pragma unroll
          for (int e2 = 0; e2 < 8; ++e2) {
            int c = l * 8 + e2;
            c ^= (c >> 3) & 7;
            float4 v = *reinterpret_cast<const float4*>(base + (c << 4));
            int jb = l * 32 + e2 * 4;
            float va[4] = {v.x, v.y, v.z, v.w};
#pragma unroll
            for (int q = 0; q < 4; ++q) {
              float vv = va[q];
              int jj = jb + q;
              if (vv > v0) { v1 = v0; i1 = i0; v0 = vv; i0 = jj; }
              else if (vv > v1) { v1 = vv; i1 = jj; }
            }
          }
        }
      }
    }
  }
#pragma unroll
  for (int rr = 0; rr < 4; ++rr) {
    int row = w * 4 + rr;
    if (l < KK) idxo[((size_t)b * NN + r0 + row) * KK + l] = oid[row][l];
  }
}

// ---------- u = (W1-W2)x, v = W2 x ----------
template <int C>
__global__ __launch_bounds__(256) void k_uv(const float* __restrict__ xin, const float* __restrict__ w,
                                            float* __restrict__ u, float* __restrict__ v) {
  const int b = blockIdx.y, n0 = blockIdx.x * 4;
  const int tid = threadIdx.x, o = tid & 63, nn = tid >> 6;
  __shared__ float wl[64][2 * C + 1];
  __shared__ float xl[4][C];
  for (int t = tid; t < 64 * 2 * C; t += 256) wl[t / (2 * C)][t % (2 * C)] = w[t];
  for (int t = tid; t < 4 * C; t += 256) xl[t / C][t % C] = xin[((size_t)b * NN + n0 + t / C) * C + t % C];
  __syncthreads();
  float s1 = 0.f, s2 = 0.f;
#pragma unroll
  for (int c = 0; c < C; ++c) {
    float xv = xl[nn][c];
    s1 = fmaf(wl[o][c], xv, s1);
    s2 = fmaf(wl[o][C + c], xv, s2);
  }
  size_t i = ((size_t)b * NN + n0 + nn) * 64 + o;
  u[i] = s1 - s2;
  v[i] = s2;
}

// ---------- stats of t1 = u[n] + v[j] ----------
__global__ __launch_bounds__(256) void k_passA(const float* __restrict__ u, const float* __restrict__ v,
                                               const int* __restrict__ idx, double* __restrict__ st) {
  const int b = blockIdx.y, n0 = blockIdx.x * 16;
  const int tid = threadIdx.x, c = tid & 63, nw = tid >> 6;
  double s = 0.0, ss = 0.0;
  for (int nn = nw; nn < 16; nn += 4) {
    size_t nb = (size_t)b * NN + n0 + nn;
    float uu = u[nb * 64 + c];
    const int* ip = idx + nb * KK;
#pragma unroll
    for (int k = 0; k < KK; ++k) {
      float val = uu + v[((size_t)b * NN + ip[k]) * 64 + c];
      double dv = (double)val;
      s += dv; ss = fma(dv, dv, ss);
    }
  }
  __shared__ double red[2][4][64];
  red[0][nw][c] = s; red[1][nw][c] = ss;
  __syncthreads();
  if (tid < 64) {
    double S = red[0][0][tid] + red[0][1][tid] + red[0][2][tid] + red[0][3][tid];
    double SS = red[1][0][tid] + red[1][1][tid] + red[1][2][tid] + red[1][3][tid];
    atomicAdd(&st[tid], S);
    atomicAdd(&st[64 + tid], SS);
  }
}

// ---------- single-stage: stats + max over k ----------
__global__ __launch_bounds__(256) void k_passAmax(const float* __restrict__ u, const float* __restrict__ v,
                                                  const int* __restrict__ idx, float* __restrict__ xout,
                                                  double* __restrict__ st) {
  const int b = blockIdx.y, n0 = blockIdx.x * 16;
  const int tid = threadIdx.x, c = tid & 63, nw = tid >> 6;
  double s = 0.0, ss = 0.0;
  for (int nn = nw; nn < 16; nn += 4) {
    size_t nb = (size_t)b * NN + n0 + nn;
    float uu = u[nb * 64 + c];
    const int* ip = idx + nb * KK;
    float mx = NEG;
#pragma unroll
    for (int k = 0; k < KK; ++k) {
      float val = uu + v[((size_t)b * NN + ip[k]) * 64 + c];
      mx = fmaxf(mx, val);
      double dv = (double)val;
      s += dv; ss = fma(dv, dv, ss);
    }
    xout[nb * 64 + c] = mx;
  }
  __shared__ double red[2][4][64];
  red[0][nw][c] = s; red[1][nw][c] = ss;
  __syncthreads();
  if (tid < 64) {
    double S = red[0][0][tid] + red[0][1][tid] + red[0][2][tid] + red[0][3][tid];
    double SS = red[1][0][tid] + red[1][1][tid] + red[1][2][tid] + red[1][3][tid];
    atomicAdd(&st[tid], S);
    atomicAdd(&st[64 + tid], SS);
  }
}

// ---------- multi-stage conv2 (r5 variant verbatim) ----------
__global__ __launch_bounds__(256) void k_passB(const float* __restrict__ u, const float* __restrict__ v,
                                               const int* __restrict__ idx, const double* __restrict__ st1,
                                               const float* __restrict__ g1, const float* __restrict__ b1,
                                               const float* __restrict__ w2, float* __restrict__ xout,
                                               double* __restrict__ st2) {
  const int b = blockIdx.y, n0 = blockIdx.x * 8;
  const int tid = threadIdx.x, lane = tid & 63, wv = tid >> 6;
  __shared__ __align__(16) float act[160][64];
  constexpr double invM = 1.0 / (double)(BB * NN * KK);
  double sm = st1[lane] * invM;
  double ad = (double)g1[lane] / sqrt(st1[64 + lane] * invM - sm * sm + EPSD);
  float a = (float)ad;
  float d = (float)((double)b1[lane] - sm * ad);
  float wr[64];
#pragma unroll
  for (int c4 = 0; c4 < 16; ++c4) {
    float4 t4 = *reinterpret_cast<const float4*>(w2 + (size_t)lane * 64 + 4 * c4);
    wr[4 * c4 + 0] = t4.x; wr[4 * c4 + 1] = t4.y; wr[4 * c4 + 2] = t4.z; wr[4 * c4 + 3] = t4.w;
  }
  for (int p = wv; p < 160; p += 4) {
    int nn = p / 20, k = p - nn * 20;
    size_t nb = (size_t)b * NN + n0 + nn;
    int j = idx[nb * KK + k];
    float val = u[nb * 64 + lane] + v[((size_t)b * NN + j) * 64 + lane];
    act[p][lane] = lrelu(fmaf(a, val, d));
  }
  __syncthreads();
  double s2 = 0.0, ss2 = 0.0;
#pragma unroll
  for (int q = 0; q < 2; ++q) {
    int nl = 2 * wv + q;
    float mx = NEG;
#pragma unroll 4
    for (int k = 0; k < KK; ++k) {
      const float* ap = &act[nl * 20 + k][0];
      float a0 = 0.f, a1 = 0.f, a2 = 0.f, a3 = 0.f;
#pragma unroll
      for (int c4 = 0; c4 < 16; ++c4) {
        float4 v4 = *reinterpret_cast<const float4*>(ap + 4 * c4);
        a0 = fmaf(wr[4 * c4 + 0], v4.x, a0);
        a1 = fmaf(wr[4 * c4 + 1], v4.y, a1);
        a2 = fmaf(wr[4 * c4 + 2], v4.z, a2);
        a3 = fmaf(wr[4 * c4 + 3], v4.w, a3);
      }
      float t2v = (a0 + a1) + (a2 + a3);
      mx = fmaxf(mx, t2v);
      double dv = (double)t2v;
      s2 += dv; ss2 = fma(dv, dv, ss2);
    }
    xout[((size_t)b * NN + n0 + nl) * 64 + lane] = mx;
  }
  __syncthreads();
  double* red = reinterpret_cast<double*>(&act[0][0]);
  red[wv * 64 + lane] = s2;
  red[256 + wv * 64 + lane] = ss2;
  __syncthreads();
  if (tid < 64) {
    double S = red[tid] + red[64 + tid] + red[128 + tid] + red[192 + tid];
    double SS = red[256 + tid] + red[320 + tid] + red[384 + tid] + red[448 + tid];
    atomicAdd(&st2[tid], S);
    atomicAdd(&st2[64 + tid], SS);
  }
}

// ---------- in-place BN+LReLU (stage 3 output) ----------
__global__ __launch_bounds__(256) void k_apply(float* __restrict__ xio, const double* __restrict__ st,
                                               const float* __restrict__ g, const float* __restrict__ bb,
                                               double invM) {
  const int b = blockIdx.y, n0 = blockIdx.x * 4;
  const int tid = threadIdx.x, c = tid & 63, nn = tid >> 6;
  double sm = st[c] * invM;
  double ad = (double)g[c] / sqrt(st[64 + c] * invM - sm * sm + EPSD);
  float a = (float)ad;
  float d = (float)((double)bb[c] - sm * ad);
  size_t i = ((size_t)b * NN + n0 + nn) * 64 + c;
  xio[i] = lrelu(fmaf(a, xio[i], d));
}

// ---------- wt transpose ----------
__global__ __launch_bounds__(256) void k_wtT(const float* __restrict__ wt, float* __restrict__ wtT) {
  int i = blockIdx.x * 256 + threadIdx.x;
  if (i < 128 * 256) { int o = i >> 8, c = i & 255; wtT[c * 128 + o] = wt[i]; }
}

// ---------- tail GEMM ----------
__global__ __launch_bounds__(256) void k_tail(const float* __restrict__ x1, const float* __restrict__ x2,
                                              const float* __restrict__ x3, const float* __restrict__ x4,
                                              const float* __restrict__ wtT, float* __restrict__ tt) {
  const int b = blockIdx.y, n0 = blockIdx.x * 16;
  const int tid = threadIdx.x, og = tid & 31, nt = tid >> 5;
  __shared__ float xc[256][20];
  const float* xs[4] = {x1, x2, x3, x4};
  for (int t = tid; t < 4096; t += 256) {
    int n = t >> 8, c = t & 255;
    xc[c][n] = xs[c >> 6][((size_t)b * NN + n0 + n) * 64 + (c & 63)];
  }
  __syncthreads();
  float acc[4][2];
#pragma unroll
  for (int r = 0; r < 4; ++r) { acc[r][0] = 0.f; acc[r][1] = 0.f; }
#pragma unroll 4
  for (int c = 0; c < 256; ++c) {
    float4 wv = *reinterpret_cast<const float4*>(&wtT[(size_t)c * 128 + 4 * og]);
    float xc0 = xc[c][2 * nt], xc1 = xc[c][2 * nt + 1];
    acc[0][0] = fmaf(wv.x, xc0, acc[0][0]); acc[0][1] = fmaf(wv.x, xc1, acc[0][1]);
    acc[1][0] = fmaf(wv.y, xc0, acc[1][0]); acc[1][1] = fmaf(wv.y, xc1, acc[1][1]);
    acc[2][0] = fmaf(wv.z, xc0, acc[2][0]); acc[2][1] = fmaf(wv.z, xc1, acc[2][1]);
    acc[3][0] = fmaf(wv.w, xc0, acc[3][0]); acc[3][1] = fmaf(wv.w, xc1, acc[3][1]);
  }
#pragma unroll
  for (int q = 0; q < 2; ++q) {
    float4 o4;
    o4.x = acc[0][q]; o4.y = acc[1][q]; o4.z = acc[2][q]; o4.w = acc[3][q];
    *reinterpret_cast<float4*>(&tt[((size_t)b * NN + n0 + 2 * nt + q) * 128 + 4 * og]) = o4;
  }
}

// ---------- tail stats ----------
__global__ __launch_bounds__(256) void k_tailstats(const float* __restrict__ tt, double* __restrict__ st) {
  const int tid = threadIdx.x, c = tid & 127, h = tid >> 7;
  const int r0 = blockIdx.x * 32;
  double s = 0.0, ss = 0.0;
  for (int rr = h; rr < 32; rr += 2) {
    double val = (double)tt[(size_t)(r0 + rr) * 128 + c];
    s += val; ss = fma(val, val, ss);
  }
  __shared__ double red[2][2][128];
  red[0][h][c] = s; red[1][h][c] = ss;
  __syncthreads();
  if (tid < 128) {
    atomicAdd(&st[tid], red[0][0][tid] + red[0][1][tid]);
    atomicAdd(&st[128 + tid], red[1][0][tid] + red[1][1][tid]);
  }
}

// ---------- tail BN+LReLU + transpose ----------
__global__ __launch_bounds__(256) void k_tailapply(const float* __restrict__ tt, const double* __restrict__ st,
                                                   const float* __restrict__ g, const float* __restrict__ bb,
                                                   float* __restrict__ out) {
  const int b = blockIdx.y, n0 = blockIdx.x * 64;
  const int tid = threadIdx.x;
  __shared__ float tl[128][65];
  constexpr double invM = 1.0 / (double)(BB * NN);
  {
    const int o = tid & 127, h = tid >> 7;
    double sm = st[o] * invM;
    double ad = (double)g[o] / sqrt(st[128 + o] * invM - sm * sm + EPSD);
    float a = (float)ad;
    float d = (float)((double)bb[o] - sm * ad);
    for (int nn2 = h; nn2 < 64; nn2 += 2) {
      float val = tt[((size_t)b * NN + n0 + nn2) * 128 + o];
      tl[o][nn2] = lrelu(fmaf(a, val, d));
    }
  }
  __syncthreads();
  {
    const int nl = tid & 63, ow = tid >> 6;
    for (int o = ow; o < 128; o += 4)
      out[((size_t)b * 128 + o) * NN + n0 + nl] = tl[o][nl];
  }
}

extern "C" void kernel_launch(void* const* d_in, const int* in_sizes, int n_in,
                              void* d_out, int out_size, void* d_ws, size_t ws_size,
                              hipStream_t stream) {
  const float* x = (const float*)d_in[0];
  const float* w0a = (const float*)d_in[1];
  const float* g0a = (const float*)d_in[2];
  const float* b0a = (const float*)d_in[3];
  const float* w0b = (const float*)d_in[4];
  const float* g0b = (const float*)d_in[5];
  const float* b0b = (const float*)d_in[6];
  const float* w1a = (const float*)d_in[7];
  const float* g1a = (const float*)d_in[8];
  const float* b1a = (const float*)d_in[9];
  const float* w1b = (const float*)d_in[10];
  const float* g1b = (const float*)d_in[11];
  const float* b1b = (const float*)d_in[12];
  const float* w2 = (const float*)d_in[13];
  const float* g2 = (const float*)d_in[14];
  const float* b2 = (const float*)d_in[15];
  const float* w3 = (const float*)d_in[16];
  const float* g3 = (const float*)d_in[17];
  const float* b3 = (const float*)d_in[18];
  const float* wt = (const float*)d_in[19];
  const float* gt = (const float*)d_in[20];
  const float* bt = (const float*)d_in[21];
  float* out = (float*)d_out;

  char* p = (char*)d_ws;
  double* stA = (double*)p; p += 2048;
  double* stB = (double*)p; p += 2048;
  double* stT = (double*)p; p += 2048;
  ushort* xh = (ushort*)p; p += (size_t)BB * NN * 64 * 2;
  ushort* xm = (ushort*)p; p += (size_t)BB * NN * 64 * 2;
  ushort* xlo = (ushort*)p; p += (size_t)BB * NN * 64 * 2;
  float* sqb = (float*)p; p += (size_t)BB * NN * 4;
  float* x0nc = (float*)p; p += (size_t)BB * NN * 6 * 4;
  float* x1 = (float*)p; p += (size_t)BB * NN * 64 * 4;
  float* x2 = (float*)p; p += (size_t)BB * NN * 64 * 4;
  float* x3 = (float*)p; p += (size_t)BB * NN * 64 * 4;
  float* x4 = (float*)p; p += (size_t)BB * NN * 64 * 4;
  float* ub = (float*)p; p += (size_t)BB * NN * 64 * 4;
  float* vb = (float*)p; p += (size_t)BB * NN * 64 * 4;
  float* ttl = (float*)p; p += (size_t)BB * NN * 128 * 4;
  float* wtTb = (float*)p; p += 128 * 256 * 4;
  int* idx = (int*)p; p += (size_t)BB * NN * KK * 4;

  constexpr double invMe = 1.0 / (double)(BB * NN * KK);
  dim3 blk(256);
  dim3 kgrid(BB * NN / 16);  // 1024 blocks, 1D: b = blk&7 for XCD/L2 affinity

  // stage 0 (multi, C=6)
  k_prep0<<<dim3(BB * NN / 256), blk, 0, stream>>>(x, x0nc, xh, xm, xlo, sqb);
  k_knnf3<32><<<kgrid, blk, 0, stream>>>(xh, xm, xlo, sqb, idx);
  k_uv<6><<<dim3(NN / 4, BB), blk, 0, stream>>>(x0nc, w0a, ub, vb);
  hipMemsetAsync(stA, 0, 4096, stream);  // stA+stB contiguous
  k_passA<<<dim3(NN / 16, BB), blk, 0, stream>>>(ub, vb, idx, stA);
  k_passB<<<dim3(NN / 8, BB), blk, 0, stream>>>(ub, vb, idx, stA, g0a, b0a, w0b, x1, stB);
  k_applyprep<<<dim3(BB * NN / 256), blk, 0, stream>>>(x1, stB, g0b, b0b, xh, xm, xlo, sqb);

  // stage 1 (multi, C=64)
  k_knnf3<64><<<kgrid, blk, 0, stream>>>(xh, xm, xlo, sqb, idx);
  k_uv<64><<<dim3(NN / 4, BB), blk, 0, stream>>>(x1, w1a, ub, vb);
  hipMemsetAsync(stA, 0, 4096, stream);
  k_passA<<<dim3(NN / 16, BB), blk, 0, stream>>>(ub, vb, idx, stA);
  k_passB<<<dim3(NN / 8, BB), blk, 0, stream>>>(ub, vb, idx, stA, g1a, b1a, w1b, x2, stB);
  k_applyprep<<<dim3(BB * NN / 256), blk, 0, stream>>>(x2, stB, g1b, b1b, xh, xm, xlo, sqb);

  // stage 2 (single)
  k_knnf3<64><<<kgrid, blk, 0, stream>>>(xh, xm, xlo, sqb, idx);
  k_uv<64><<<dim3(NN / 4, BB), blk, 0, stream>>>(x2, w2, ub, vb);
  hipMemsetAsync(stA, 0, 2048, stream);
  k_passAmax<<<dim3(NN / 16, BB), blk, 0, stream>>>(ub, vb, idx, x3, stA);
  k_applyprep<<<dim3(BB * NN / 256), blk, 0, stream>>>(x3, stA, g2, b2, xh, xm, xlo, sqb);

  // stage 3 (single)
  k_knnf3<64><<<kgrid, blk, 0, stream>>>(xh, xm, xlo, sqb, idx);
  k_uv<64><<<dim3(NN / 4, BB), blk, 0, stream>>>(x3, w3, ub, vb);
  hipMemsetAsync(stA, 0, 2048, stream);
  k_passAmax<<<dim3(NN / 16, BB), blk, 0, stream>>>(ub, vb, idx, x4, stA);
  k_apply<<<dim3(NN / 4, BB), blk, 0, stream>>>(x4, stA, g3, b3, invMe);

  // tail
  k_wtT<<<dim3(128), blk, 0, stream>>>(wt, wtTb);
  k_tail<<<dim3(NN / 16, BB), blk, 0, stream>>>(x1, x2, x3, x4, wtTb, ttl);
  hipMemsetAsync(stT, 0, 2048, stream);
  k_tailstats<<<dim3(512), blk, 0, stream>>>(ttl, stT);
  k_tailapply<<<dim3(NN / 64, BB), blk, 0, stream>>>(ttl, stT, gt, bt, out);
}

// Round 11
// 1202.802 us; speedup vs baseline: 3.1501x; 1.3106x over previous
//
#include <hip/hip_runtime.h>

constexpr int BB = 8, NN = 2048, KK = 20;
constexpr float SLP = 0.2f;
constexpr float NEG = -3.0e38f;    // extracted-mark
constexpr float EMPTYV = -3.3e38f; // cache-empty sentinel
constexpr double EPSD = 1e-5;

typedef short short8 __attribute__((ext_vector_type(8)));
typedef float f32x4 __attribute__((ext_vector_type(4)));
typedef unsigned short ushort;

__device__ __forceinline__ float lrelu(float v) { return v >= 0.f ? v : SLP * v; }

__device__ __forceinline__ float bits2f(unsigned u) { union { unsigned u; float f; } a; a.u = u; return a.f; }
__device__ __forceinline__ unsigned f2bits(float f) { union { float f; unsigned u; } a; a.f = f; return a.u; }

__device__ __forceinline__ ushort bf16rne(float f) {
  unsigned u = f2bits(f);
  return (ushort)((u + 0x7fffu + ((u >> 16) & 1u)) >> 16);
}

__device__ __forceinline__ void split3(float x, ushort& h, ushort& m, ushort& l) {
  h = bf16rne(x);
  float fh = bits2f(((unsigned)h) << 16);
  float t1 = x - fh;
  m = bf16rne(t1);
  float fm = bits2f(((unsigned)m) << 16);
  float t2 = t1 - fm;
  l = bf16rne(t2);
}

// ---------- prep stage 0 ----------
__global__ __launch_bounds__(256) void k_prep0(const float* __restrict__ x, float* __restrict__ x0nc,
                                               ushort* __restrict__ xh, ushort* __restrict__ xm,
                                               ushort* __restrict__ xlo, float* __restrict__ sqb) {
  int i = blockIdx.x * 256 + threadIdx.x;
  if (i >= BB * NN) return;
  int b = i >> 11, n = i & (NN - 1);
  float v[6];
#pragma unroll
  for (int c = 0; c < 6; ++c) v[c] = x[((size_t)b * 6 + c) * NN + n];
  float s = 0.f;
#pragma unroll
  for (int c = 0; c < 6; ++c) s = __fadd_rn(s, __fmul_rn(v[c], v[c]));
  sqb[i] = s;
#pragma unroll
  for (int c = 0; c < 6; ++c) x0nc[(size_t)i * 6 + c] = v[c];
  size_t base = (size_t)i * 32;
#pragma unroll
  for (int c = 0; c < 32; ++c) {
    float xv = (c < 6) ? v[c] : 0.f;
    ushort h, m, l;
    split3(xv, h, m, l);
    xh[base + c] = h; xm[base + c] = m; xlo[base + c] = l;
  }
}

// ---------- fused BN+LReLU apply + split prep ----------
__global__ __launch_bounds__(256) void k_applyprep(float* __restrict__ xio, const double* __restrict__ st,
                                                   const float* __restrict__ g, const float* __restrict__ bb,
                                                   ushort* __restrict__ xh, ushort* __restrict__ xm,
                                                   ushort* __restrict__ xlo, float* __restrict__ sqb) {
  __shared__ float sa[64], sd[64];
  const int tid = threadIdx.x;
  if (tid < 64) {
    constexpr double invM = 1.0 / (double)(BB * NN * KK);
    double sm = st[tid] * invM;
    double ad = (double)g[tid] / sqrt(st[64 + tid] * invM - sm * sm + EPSD);
    sa[tid] = (float)ad;
    sd[tid] = (float)((double)bb[tid] - sm * ad);
  }
  __syncthreads();
  int i = blockIdx.x * 256 + tid;
  float* src = xio + (size_t)i * 64;
  float v[64];
#pragma unroll
  for (int c4 = 0; c4 < 16; ++c4) {
    float4 t = *reinterpret_cast<const float4*>(src + 4 * c4);
    v[4 * c4 + 0] = t.x; v[4 * c4 + 1] = t.y; v[4 * c4 + 2] = t.z; v[4 * c4 + 3] = t.w;
  }
#pragma unroll
  for (int c = 0; c < 64; ++c) v[c] = lrelu(fmaf(sa[c], v[c], sd[c]));
  float s = 0.f;
#pragma unroll
  for (int c = 0; c < 64; ++c) s = __fadd_rn(s, __fmul_rn(v[c], v[c]));
  sqb[i] = s;
#pragma unroll
  for (int c4 = 0; c4 < 16; ++c4) {
    float4 t;
    t.x = v[4 * c4 + 0]; t.y = v[4 * c4 + 1]; t.z = v[4 * c4 + 2]; t.w = v[4 * c4 + 3];
    *reinterpret_cast<float4*>(src + 4 * c4) = t;
  }
  size_t base = (size_t)i * 64;
#pragma unroll
  for (int c = 0; c < 64; ++c) {
    ushort h, m, l;
    split3(v[c], h, m, l);
    xh[base + c] = h; xm[base + c] = m; xlo[base + c] = l;
  }
}

// ---------- FUSED kNN v4: two 1024-col halves reuse one 66KB LDS buffer -> 2 blocks/CU ----------
// Half 0: r5 extraction select (20 tournament extractions). Half 1: streaming merge with
// threshold gate + r2's shfl_up sorted insert. Exact; idx bit-identical to r5 path.
template <int CP>
__global__ __launch_bounds__(256) void k_knnf4(const ushort* __restrict__ xh, const ushort* __restrict__ xm,
                                               const ushort* __restrict__ xlo, const float* __restrict__ sqb,
                                               int* __restrict__ idxo) {
  constexpr int KS = CP / 32;
  constexpr int RS = 1028;  // floats per row
  const int blk = blockIdx.x;
  const int b = blk & 7;
  const int r0 = (blk >> 3) * 16;
  const int tid = threadIdx.x, w = tid >> 6, l = tid & 63;
  const size_t xb = (size_t)b * NN * CP;
  const int ko = (l >> 4) * 8;

  __shared__ __align__(16) float sc[16 * RS];
  __shared__ float lv[16][20];
  __shared__ int li[16][20];

  short8 Ah[KS], Am[KS], Al[KS];
  {
    const int ar = r0 + (l & 15);
#pragma unroll
    for (int ks = 0; ks < KS; ++ks) {
      size_t o = xb + (size_t)ar * CP + ks * 32 + ko;
      Ah[ks] = *reinterpret_cast<const short8*>(xh + o);
      Am[ks] = *reinterpret_cast<const short8*>(xm + o);
      Al[ks] = *reinterpret_cast<const short8*>(xlo + o);
    }
  }
  float sqi[4];
#pragma unroll
  for (int q = 0; q < 4; ++q) sqi[q] = sqb[b * NN + r0 + (l >> 4) * 4 + q];

  for (int H = 0; H < 2; ++H) {
    // ---- compute phase: wave w covers col-tiles H*64 + w*16 + [0,16) ----
    int ct = H * 64 + w * 16;
    short8 Bh[KS], Bm[KS], Bl[KS], Ch[KS], Cm[KS], Cl[KS];
#pragma unroll
    for (int ks = 0; ks < KS; ++ks) {
      size_t o = xb + (size_t)(ct * 16 + (l & 15)) * CP + ks * 32 + ko;
      Bh[ks] = *reinterpret_cast<const short8*>(xh + o);
      Bm[ks] = *reinterpret_cast<const short8*>(xm + o);
      Bl[ks] = *reinterpret_cast<const short8*>(xlo + o);
    }
    for (int t = 0; t < 16; ++t) {
      if (t < 15) {
#pragma unroll
        for (int ks = 0; ks < KS; ++ks) {
          size_t o = xb + (size_t)((ct + 1) * 16 + (l & 15)) * CP + ks * 32 + ko;
          Ch[ks] = *reinterpret_cast<const short8*>(xh + o);
          Cm[ks] = *reinterpret_cast<const short8*>(xm + o);
          Cl[ks] = *reinterpret_cast<const short8*>(xlo + o);
        }
      }
      f32x4 acc = {0.f, 0.f, 0.f, 0.f};
#pragma unroll
      for (int ks = 0; ks < KS; ++ks) {
        acc = __builtin_amdgcn_mfma_f32_16x16x32_bf16(Am[ks], Bm[ks], acc, 0, 0, 0);
        acc = __builtin_amdgcn_mfma_f32_16x16x32_bf16(Ah[ks], Bl[ks], acc, 0, 0, 0);
        acc = __builtin_amdgcn_mfma_f32_16x16x32_bf16(Al[ks], Bh[ks], acc, 0, 0, 0);
        acc = __builtin_amdgcn_mfma_f32_16x16x32_bf16(Ah[ks], Bm[ks], acc, 0, 0, 0);
        acc = __builtin_amdgcn_mfma_f32_16x16x32_bf16(Am[ks], Bh[ks], acc, 0, 0, 0);
        acc = __builtin_amdgcn_mfma_f32_16x16x32_bf16(Ah[ks], Bh[ks], acc, 0, 0, 0);
      }
      int col = ct * 16 + (l & 15);
      float sqj = sqb[b * NN + col];
      int cl = col - H * 1024;
      int chunk = cl >> 2;
      int cs = chunk ^ ((chunk >> 3) & 7);
#pragma unroll
      for (int q = 0; q < 4; ++q) {
        float s = __fsub_rn(__fsub_rn(2.f * acc[q], sqi[q]), sqj);
        sc[((l >> 4) * 4 + q) * RS + cs * 4 + (cl & 3)] = s;
      }
#pragma unroll
      for (int ks = 0; ks < KS; ++ks) { Bh[ks] = Ch[ks]; Bm[ks] = Cm[ks]; Bl[ks] = Cl[ks]; }
      ++ct;
    }
    __syncthreads();

    // ---- select phase: wave w owns rows w*4..w*4+3; lane l owns cols l*16..l*16+15 of this half ----
    for (int rr = 0; rr < 4; ++rr) {
      const int row = w * 4 + rr;
      float* base = &sc[row * RS];
      float v0 = EMPTYV, v1 = EMPTYV;
      int i0 = -1, i1 = -1;
#pragma unroll
      for (int e = 0; e < 4; ++e) {
        int c = l * 4 + e;
        int cs = c ^ ((c >> 3) & 7);
        float4 v = *reinterpret_cast<const float4*>(base + cs * 4);
        int jb = H * 1024 + l * 16 + e * 4;
        float va[4] = {v.x, v.y, v.z, v.w};
#pragma unroll
        for (int q = 0; q < 4; ++q) {
          float vv = va[q];
          int jj = jb + q;
          if (vv > v0) { v1 = v0; i1 = i0; v0 = vv; i0 = jj; }
          else if (vv > v1) { v1 = vv; i1 = jj; }
        }
      }
      if (H == 0) {
        for (int e = 0; e < KK; ++e) {
          float m = v0;
#pragma unroll
          for (int d = 1; d < 64; d <<= 1) m = fmaxf(m, __shfl_xor(m, d));
          unsigned long long msk = __ballot(v0 == m);
          int wl = __ffsll((unsigned long long)msk) - 1;
          if (l == wl) {
            lv[row][e] = v0; li[row][e] = i0;
            int cl2 = i0 - H * 1024;
            int cc = cl2 >> 2;
            int cs2 = cc ^ ((cc >> 3) & 7);
            base[cs2 * 4 + (cl2 & 3)] = NEG;
            v0 = v1; i0 = i1; v1 = EMPTYV; i1 = -1;
            if (v0 <= EMPTYV) {
              v0 = EMPTYV; v1 = EMPTYV; i0 = -1; i1 = -1;
#pragma unroll
              for (int e2 = 0; e2 < 4; ++e2) {
                int c = l * 4 + e2;
                int cs3 = c ^ ((c >> 3) & 7);
                float4 v = *reinterpret_cast<const float4*>(base + cs3 * 4);
                int jb = H * 1024 + l * 16 + e2 * 4;
                float va[4] = {v.x, v.y, v.z, v.w};
#pragma unroll
                for (int q = 0; q < 4; ++q) {
                  float vv = va[q];
                  int jj = jb + q;
                  if (vv > v0) { v1 = v0; i1 = i0; v0 = vv; i0 = jj; }
                  else if (vv > v1) { v1 = vv; i1 = jj; }
                }
              }
            }
          }
        }
      } else {
        float t19 = lv[row][19];
        while (true) {
          float m = v0;
#pragma unroll
          for (int d = 1; d < 64; d <<= 1) m = fmaxf(m, __shfl_xor(m, d));
          if (!(m > t19)) break;  // strict: half-1 value-ties (larger idx) correctly lose
          unsigned long long msk = __ballot(v0 == m);
          int wl = __ffsll((unsigned long long)msk) - 1;
          int nj = __shfl(i0, wl);
          // exact sorted insert (r2-proven shfl_up shift); pos = #(entries >= m)
          float mylv = (l < 20) ? lv[row][l] : EMPTYV;
          int myli_ = (l < 20) ? li[row][l] : 0;
          unsigned long long gm = __ballot(mylv > m || mylv == m);
          int pos = __popcll(gm);
          float pv = __shfl_up(mylv, 1);
          int pi = __shfl_up(myli_, 1);
          float nv = (l == pos) ? m : (l < pos ? mylv : pv);
          int ni = (l == pos) ? nj : (l < pos ? myli_ : pi);
          if (l < 20) { lv[row][l] = nv; li[row][l] = ni; }
          t19 = __shfl(nv, 19);
          if (l == wl) {
            int cl2 = i0 - H * 1024;
            int cc = cl2 >> 2;
            int cs2 = cc ^ ((cc >> 3) & 7);
            base[cs2 * 4 + (cl2 & 3)] = NEG;
            v0 = v1; i0 = i1; v1 = EMPTYV; i1 = -1;
            if (v0 <= EMPTYV) {
              v0 = EMPTYV; v1 = EMPTYV; i0 = -1; i1 = -1;
#pragma unroll
              for (int e2 = 0; e2 < 4; ++e2) {
                int c = l * 4 + e2;
                int cs3 = c ^ ((c >> 3) & 7);
                float4 v = *reinterpret_cast<const float4*>(base + cs3 * 4);
                int jb = H * 1024 + l * 16 + e2 * 4;
                float va[4] = {v.x, v.y, v.z, v.w};
#pragma unroll
                for (int q = 0; q < 4; ++q) {
                  float vv = va[q];
                  int jj = jb + q;
                  if (vv > v0) { v1 = v0; i1 = i0; v0 = vv; i0 = jj; }
                  else if (vv > v1) { v1 = vv; i1 = jj; }
                }
              }
            }
          }
        }
      }
    }
    __syncthreads();  // select done before next half overwrites sc
  }
#pragma unroll
  for (int rr = 0; rr < 4; ++rr) {
    int row = w * 4 + rr;
    if (l < KK) idxo[((size_t)b * NN + r0 + row) * KK + l] = li[row][l];
  }
}

// ---------- u = (W1-W2)x, v = W2 x ----------
template <int C>
__global__ __launch_bounds__(256) void k_uv(const float* __restrict__ xin, const float* __restrict__ w,
                                            float* __restrict__ u, float* __restrict__ v) {
  const int b = blockIdx.y, n0 = blockIdx.x * 4;
  const int tid = threadIdx.x, o = tid & 63, nn = tid >> 6;
  __shared__ float wl[64][2 * C + 1];
  __shared__ float xl[4][C];
  for (int t = tid; t < 64 * 2 * C; t += 256) wl[t / (2 * C)][t % (2 * C)] = w[t];
  for (int t = tid; t < 4 * C; t += 256) xl[t / C][t % C] = xin[((size_t)b * NN + n0 + t / C) * C + t % C];
  __syncthreads();
  float s1 = 0.f, s2 = 0.f;
#pragma unroll
  for (int c = 0; c < C; ++c) {
    float xv = xl[nn][c];
    s1 = fmaf(wl[o][c], xv, s1);
    s2 = fmaf(wl[o][C + c], xv, s2);
  }
  size_t i = ((size_t)b * NN + n0 + nn) * 64 + o;
  u[i] = s1 - s2;
  v[i] = s2;
}

// ---------- stats of t1 = u[n] + v[j] ----------
__global__ __launch_bounds__(256) void k_passA(const float* __restrict__ u, const float* __restrict__ v,
                                               const int* __restrict__ idx, double* __restrict__ st) {
  const int b = blockIdx.y, n0 = blockIdx.x * 16;
  const int tid = threadIdx.x, c = tid & 63, nw = tid >> 6;
  double s = 0.0, ss = 0.0;
  for (int nn = nw; nn < 16; nn += 4) {
    size_t nb = (size_t)b * NN + n0 + nn;
    float uu = u[nb * 64 + c];
    const int* ip = idx + nb * KK;
#pragma unroll
    for (int k = 0; k < KK; ++k) {
      float val = uu + v[((size_t)b * NN + ip[k]) * 64 + c];
      double dv = (double)val;
      s += dv; ss = fma(dv, dv, ss);
    }
  }
  __shared__ double red[2][4][64];
  red[0][nw][c] = s; red[1][nw][c] = ss;
  __syncthreads();
  if (tid < 64) {
    double S = red[0][0][tid] + red[0][1][tid] + red[0][2][tid] + red[0][3][tid];
    double SS = red[1][0][tid] + red[1][1][tid] + red[1][2][tid] + red[1][3][tid];
    atomicAdd(&st[tid], S);
    atomicAdd(&st[64 + tid], SS);
  }
}

// ---------- single-stage: stats + max over k ----------
__global__ __launch_bounds__(256) void k_passAmax(const float* __restrict__ u, const float* __restrict__ v,
                                                  const int* __restrict__ idx, float* __restrict__ xout,
                                                  double* __restrict__ st) {
  const int b = blockIdx.y, n0 = blockIdx.x * 16;
  const int tid = threadIdx.x, c = tid & 63, nw = tid >> 6;
  double s = 0.0, ss = 0.0;
  for (int nn = nw; nn < 16; nn += 4) {
    size_t nb = (size_t)b * NN + n0 + nn;
    float uu = u[nb * 64 + c];
    const int* ip = idx + nb * KK;
    float mx = NEG;
#pragma unroll
    for (int k = 0; k < KK; ++k) {
      float val = uu + v[((size_t)b * NN + ip[k]) * 64 + c];
      mx = fmaxf(mx, val);
      double dv = (double)val;
      s += dv; ss = fma(dv, dv, ss);
    }
    xout[nb * 64 + c] = mx;
  }
  __shared__ double red[2][4][64];
  red[0][nw][c] = s; red[1][nw][c] = ss;
  __syncthreads();
  if (tid < 64) {
    double S = red[0][0][tid] + red[0][1][tid] + red[0][2][tid] + red[0][3][tid];
    double SS = red[1][0][tid] + red[1][1][tid] + red[1][2][tid] + red[1][3][tid];
    atomicAdd(&st[tid], S);
    atomicAdd(&st[64 + tid], SS);
  }
}

// ---------- multi-stage conv2 (r5 variant verbatim) ----------
__global__ __launch_bounds__(256) void k_passB(const float* __restrict__ u, const float* __restrict__ v,
                                               const int* __restrict__ idx, const double* __restrict__ st1,
                                               const float* __restrict__ g1, const float* __restrict__ b1,
                                               const float* __restrict__ w2, float* __restrict__ xout,
                                               double* __restrict__ st2) {
  const int b = blockIdx.y, n0 = blockIdx.x * 8;
  const int tid = threadIdx.x, lane = tid & 63, wv = tid >> 6;
  __shared__ __align__(16) float act[160][64];
  constexpr double invM = 1.0 / (double)(BB * NN * KK);
  double sm = st1[lane] * invM;
  double ad = (double)g1[lane] / sqrt(st1[64 + lane] * invM - sm * sm + EPSD);
  float a = (float)ad;
  float d = (float)((double)b1[lane] - sm * ad);
  float wr[64];
#pragma unroll
  for (int c4 = 0; c4 < 16; ++c4) {
    float4 t4 = *reinterpret_cast<const float4*>(w2 + (size_t)lane * 64 + 4 * c4);
    wr[4 * c4 + 0] = t4.x; wr[4 * c4 + 1] = t4.y; wr[4 * c4 + 2] = t4.z; wr[4 * c4 + 3] = t4.w;
  }
  for (int p = wv; p < 160; p += 4) {
    int nn = p / 20, k = p - nn * 20;
    size_t nb = (size_t)b * NN + n0 + nn;
    int j = idx[nb * KK + k];
    float val = u[nb * 64 + lane] + v[((size_t)b * NN + j) * 64 + lane];
    act[p][lane] = lrelu(fmaf(a, val, d));
  }
  __syncthreads();
  double s2 = 0.0, ss2 = 0.0;
#pragma unroll
  for (int q = 0; q < 2; ++q) {
    int nl = 2 * wv + q;
    float mx = NEG;
#pragma unroll 4
    for (int k = 0; k < KK; ++k) {
      const float* ap = &act[nl * 20 + k][0];
      float a0 = 0.f, a1 = 0.f, a2 = 0.f, a3 = 0.f;
#pragma unroll
      for (int c4 = 0; c4 < 16; ++c4) {
        float4 v4 = *reinterpret_cast<const float4*>(ap + 4 * c4);
        a0 = fmaf(wr[4 * c4 + 0], v4.x, a0);
        a1 = fmaf(wr[4 * c4 + 1], v4.y, a1);
        a2 = fmaf(wr[4 * c4 + 2], v4.z, a2);
        a3 = fmaf(wr[4 * c4 + 3], v4.w, a3);
      }
      float t2v = (a0 + a1) + (a2 + a3);
      mx = fmaxf(mx, t2v);
      double dv = (double)t2v;
      s2 += dv; ss2 = fma(dv, dv, ss2);
    }
    xout[((size_t)b * NN + n0 + nl) * 64 + lane] = mx;
  }
  __syncthreads();
  double* red = reinterpret_cast<double*>(&act[0][0]);
  red[wv * 64 + lane] = s2;
  red[256 + wv * 64 + lane] = ss2;
  __syncthreads();
  if (tid < 64) {
    double S = red[tid] + red[64 + tid] + red[128 + tid] + red[192 + tid];
    double SS = red[256 + tid] + red[320 + tid] + red[384 + tid] + red[448 + tid];
    atomicAdd(&st2[tid], S);
    atomicAdd(&st2[64 + tid], SS);
  }
}

// ---------- in-place BN+LReLU (stage 3 output) ----------
__global__ __launch_bounds__(256) void k_apply(float* __restrict__ xio, const double* __restrict__ st,
                                               const float* __restrict__ g, const float* __restrict__ bb,
                                               double invM) {
  const int b = blockIdx.y, n0 = blockIdx.x * 4;
  const int tid = threadIdx.x, c = tid & 63, nn = tid >> 6;
  double sm = st[c] * invM;
  double ad = (double)g[c] / sqrt(st[64 + c] * invM - sm * sm + EPSD);
  float a = (float)ad;
  float d = (float)((double)bb[c] - sm * ad);
  size_t i = ((size_t)b * NN + n0 + nn) * 64 + c;
  xio[i] = lrelu(fmaf(a, xio[i], d));
}

// ---------- wt transpose ----------
__global__ __launch_bounds__(256) void k_wtT(const float* __restrict__ wt, float* __restrict__ wtT) {
  int i = blockIdx.x * 256 + threadIdx.x;
  if (i < 128 * 256) { int o = i >> 8, c = i & 255; wtT[c * 128 + o] = wt[i]; }
}

// ---------- tail GEMM ----------
__global__ __launch_bounds__(256) void k_tail(const float* __restrict__ x1, const float* __restrict__ x2,
                                              const float* __restrict__ x3, const float* __restrict__ x4,
                                              const float* __restrict__ wtT, float* __restrict__ tt) {
  const int b = blockIdx.y, n0 = blockIdx.x * 16;
  const int tid = threadIdx.x, og = tid & 31, nt = tid >> 5;
  __shared__ float xc[256][20];
  const float* xs[4] = {x1, x2, x3, x4};
  for (int t = tid; t < 4096; t += 256) {
    int n = t >> 8, c = t & 255;
    xc[c][n] = xs[c >> 6][((size_t)b * NN + n0 + n) * 64 + (c & 63)];
  }
  __syncthreads();
  float acc[4][2];
#pragma unroll
  for (int r = 0; r < 4; ++r) { acc[r][0] = 0.f; acc[r][1] = 0.f; }
#pragma unroll 4
  for (int c = 0; c < 256; ++c) {
    float4 wv = *reinterpret_cast<const float4*>(&wtT[(size_t)c * 128 + 4 * og]);
    float xc0 = xc[c][2 * nt], xc1 = xc[c][2 * nt + 1];
    acc[0][0] = fmaf(wv.x, xc0, acc[0][0]); acc[0][1] = fmaf(wv.x, xc1, acc[0][1]);
    acc[1][0] = fmaf(wv.y, xc0, acc[1][0]); acc[1][1] = fmaf(wv.y, xc1, acc[1][1]);
    acc[2][0] = fmaf(wv.z, xc0, acc[2][0]); acc[2][1] = fmaf(wv.z, xc1, acc[2][1]);
    acc[3][0] = fmaf(wv.w, xc0, acc[3][0]); acc[3][1] = fmaf(wv.w, xc1, acc[3][1]);
  }
#pragma unroll
  for (int q = 0; q < 2; ++q) {
    float4 o4;
    o4.x = acc[0][q]; o4.y = acc[1][q]; o4.z = acc[2][q]; o4.w = acc[3][q];
    *reinterpret_cast<float4*>(&tt[((size_t)b * NN + n0 + 2 * nt + q) * 128 + 4 * og]) = o4;
  }
}

// ---------- tail stats ----------
__global__ __launch_bounds__(256) void k_tailstats(const float* __restrict__ tt, double* __restrict__ st) {
  const int tid = threadIdx.x, c = tid & 127, h = tid >> 7;
  const int r0 = blockIdx.x * 32;
  double s = 0.0, ss = 0.0;
  for (int rr = h; rr < 32; rr += 2) {
    double val = (double)tt[(size_t)(r0 + rr) * 128 + c];
    s += val; ss = fma(val, val, ss);
  }
  __shared__ double red[2][2][128];
  red[0][h][c] = s; red[1][h][c] = ss;
  __syncthreads();
  if (tid < 128) {
    atomicAdd(&st[tid], red[0][0][tid] + red[0][1][tid]);
    atomicAdd(&st[128 + tid], red[1][0][tid] + red[1][1][tid]);
  }
}

// ---------- tail BN+LReLU + transpose ----------
__global__ __launch_bounds__(256) void k_tailapply(const float* __restrict__ tt, const double* __restrict__ st,
                                                   const float* __restrict__ g, const float* __restrict__ bb,
                                                   float* __restrict__ out) {
  const int b = blockIdx.y, n0 = blockIdx.x * 64;
  const int tid = threadIdx.x;
  __shared__ float tl[128][65];
  constexpr double invM = 1.0 / (double)(BB * NN);
  {
    const int o = tid & 127, h = tid >> 7;
    double sm = st[o] * invM;
    double ad = (double)g[o] / sqrt(st[128 + o] * invM - sm * sm + EPSD);
    float a = (float)ad;
    float d = (float)((double)bb[o] - sm * ad);
    for (int nn2 = h; nn2 < 64; nn2 += 2) {
      float val = tt[((size_t)b * NN + n0 + nn2) * 128 + o];
      tl[o][nn2] = lrelu(fmaf(a, val, d));
    }
  }
  __syncthreads();
  {
    const int nl = tid & 63, ow = tid >> 6;
    for (int o = ow; o < 128; o += 4)
      out[((size_t)b * 128 + o) * NN + n0 + nl] = tl[o][nl];
  }
}

extern "C" void kernel_launch(void* const* d_in, const int* in_sizes, int n_in,
                              void* d_out, int out_size, void* d_ws, size_t ws_size,
                              hipStream_t stream) {
  const float* x = (const float*)d_in[0];
  const float* w0a = (const float*)d_in[1];
  const float* g0a = (const float*)d_in[2];
  const float* b0a = (const float*)d_in[3];
  const float* w0b = (const float*)d_in[4];
  const float* g0b = (const float*)d_in[5];
  const float* b0b = (const float*)d_in[6];
  const float* w1a = (const float*)d_in[7];
  const float* g1a = (const float*)d_in[8];
  const float* b1a = (const float*)d_in[9];
  const float* w1b = (const float*)d_in[10];
  const float* g1b = (const float*)d_in[11];
  const float* b1b = (const float*)d_in[12];
  const float* w2 = (const float*)d_in[13];
  const float* g2 = (const float*)d_in[14];
  const float* b2 = (const float*)d_in[15];
  const float* w3 = (const float*)d_in[16];
  const float* g3 = (const float*)d_in[17];
  const float* b3 = (const float*)d_in[18];
  const float* wt = (const float*)d_in[19];
  const float* gt = (const float*)d_in[20];
  const float* bt = (const float*)d_in[21];
  float* out = (float*)d_out;

  char* p = (char*)d_ws;
  double* stA = (double*)p; p += 2048;
  double* stB = (double*)p; p += 2048;
  double* stT = (double*)p; p += 2048;
  ushort* xh = (ushort*)p; p += (size_t)BB * NN * 64 * 2;
  ushort* xm = (ushort*)p; p += (size_t)BB * NN * 64 * 2;
  ushort* xlo = (ushort*)p; p += (size_t)BB * NN * 64 * 2;
  float* sqb = (float*)p; p += (size_t)BB * NN * 4;
  float* x0nc = (float*)p; p += (size_t)BB * NN * 6 * 4;
  float* x1 = (float*)p; p += (size_t)BB * NN * 64 * 4;
  float* x2 = (float*)p; p += (size_t)BB * NN * 64 * 4;
  float* x3 = (float*)p; p += (size_t)BB * NN * 64 * 4;
  float* x4 = (float*)p; p += (size_t)BB * NN * 64 * 4;
  float* ub = (float*)p; p += (size_t)BB * NN * 64 * 4;
  float* vb = (float*)p; p += (size_t)BB * NN * 64 * 4;
  float* ttl = (float*)p; p += (size_t)BB * NN * 128 * 4;
  float* wtTb = (float*)p; p += 128 * 256 * 4;
  int* idx = (int*)p; p += (size_t)BB * NN * KK * 4;

  constexpr double invMe = 1.0 / (double)(BB * NN * KK);
  dim3 blk(256);
  dim3 kgrid(BB * NN / 16);  // 1024 blocks; b = blk&7 for XCD/L2 affinity

  // stage 0 (multi, C=6)
  k_prep0<<<dim3(BB * NN / 256), blk, 0, stream>>>(x, x0nc, xh, xm, xlo, sqb);
  k_knnf4<32><<<kgrid, blk, 0, stream>>>(xh, xm, xlo, sqb, idx);
  k_uv<6><<<dim3(NN / 4, BB), blk, 0, stream>>>(x0nc, w0a, ub, vb);
  hipMemsetAsync(stA, 0, 4096, stream);  // stA+stB contiguous
  k_passA<<<dim3(NN / 16, BB), blk, 0, stream>>>(ub, vb, idx, stA);
  k_passB<<<dim3(NN / 8, BB), blk, 0, stream>>>(ub, vb, idx, stA, g0a, b0a, w0b, x1, stB);
  k_applyprep<<<dim3(BB * NN / 256), blk, 0, stream>>>(x1, stB, g0b, b0b, xh, xm, xlo, sqb);

  // stage 1 (multi, C=64)
  k_knnf4<64><<<kgrid, blk, 0, stream>>>(xh, xm, xlo, sqb, idx);
  k_uv<64><<<dim3(NN / 4, BB), blk, 0, stream>>>(x1, w1a, ub, vb);
  hipMemsetAsync(stA, 0, 4096, stream);
  k_passA<<<dim3(NN / 16, BB), blk, 0, stream>>>(ub, vb, idx, stA);
  k_passB<<<dim3(NN / 8, BB), blk, 0, stream>>>(ub, vb, idx, stA, g1a, b1a, w1b, x2, stB);
  k_applyprep<<<dim3(BB * NN / 256), blk, 0, stream>>>(x2, stB, g1b, b1b, xh, xm, xlo, sqb);

  // stage 2 (single)
  k_knnf4<64><<<kgrid, blk, 0, stream>>>(xh, xm, xlo, sqb, idx);
  k_uv<64><<<dim3(NN / 4, BB), blk, 0, stream>>>(x2, w2, ub, vb);
  hipMemsetAsync(stA, 0, 2048, stream);
  k_passAmax<<<dim3(NN / 16, BB), blk, 0, stream>>>(ub, vb, idx, x3, stA);
  k_applyprep<<<dim3(BB * NN / 256), blk, 0, stream>>>(x3, stA, g2, b2, xh, xm, xlo, sqb);

  // stage 3 (single)
  k_knnf4<64><<<kgrid, blk, 0, stream>>>(xh, xm, xlo, sqb, idx);
  k_uv<64><<<dim3(NN / 4, BB), blk, 0, stream>>>(x3, w3, ub, vb);
  hipMemsetAsync(stA, 0, 2048, stream);
  k_passAmax<<<dim3(NN / 16, BB), blk, 0, stream>>>(ub, vb, idx, x4, stA);
  k_apply<<<dim3(NN / 4, BB), blk, 0, stream>>>(x4, stA, g3, b3, invMe);

  // tail
  k_wtT<<<dim3(128), blk, 0, stream>>>(wt, wtTb);
  k_tail<<<dim3(NN / 16, BB), blk, 0, stream>>>(x1, x2, x3, x4, wtTb, ttl);
  hipMemsetAsync(stT, 0, 2048, stream);
  k_tailstats<<<dim3(512), blk, 0, stream>>>(ttl, stT);
  k_tailapply<<<dim3(NN / 64, BB), blk, 0, stream>>>(ttl, stT, gt, bt, out);
}

// Round 12
// 1066.628 us; speedup vs baseline: 3.5523x; 1.1277x over previous
//
#include <hip/hip_runtime.h>

constexpr int BB = 8, NN = 2048, KK = 20;
constexpr float SLP = 0.2f;
constexpr float NEG = -3.0e38f;    // extracted-mark
constexpr float EMPTYV = -3.3e38f; // cache-empty sentinel
constexpr double EPSD = 1e-5;

typedef short short8 __attribute__((ext_vector_type(8)));
typedef float f32x4 __attribute__((ext_vector_type(4)));
typedef unsigned short ushort;

__device__ __forceinline__ float lrelu(float v) { return v >= 0.f ? v : SLP * v; }

__device__ __forceinline__ float bits2f(unsigned u) { union { unsigned u; float f; } a; a.u = u; return a.f; }
__device__ __forceinline__ unsigned f2bits(float f) { union { float f; unsigned u; } a; a.f = f; return a.u; }

__device__ __forceinline__ ushort bf16rne(float f) {
  unsigned u = f2bits(f);
  return (ushort)((u + 0x7fffu + ((u >> 16) & 1u)) >> 16);
}

__device__ __forceinline__ void split3(float x, ushort& h, ushort& m, ushort& l) {
  h = bf16rne(x);
  float fh = bits2f(((unsigned)h) << 16);
  float t1 = x - fh;
  m = bf16rne(t1);
  float fm = bits2f(((unsigned)m) << 16);
  float t2 = t1 - fm;
  l = bf16rne(t2);
}

// ---------- prep stage 0 ----------
__global__ __launch_bounds__(256) void k_prep0(const float* __restrict__ x, float* __restrict__ x0nc,
                                               ushort* __restrict__ xh, ushort* __restrict__ xm,
                                               ushort* __restrict__ xlo, float* __restrict__ sqb) {
  int i = blockIdx.x * 256 + threadIdx.x;
  if (i >= BB * NN) return;
  int b = i >> 11, n = i & (NN - 1);
  float v[6];
#pragma unroll
  for (int c = 0; c < 6; ++c) v[c] = x[((size_t)b * 6 + c) * NN + n];
  float s = 0.f;
#pragma unroll
  for (int c = 0; c < 6; ++c) s = __fadd_rn(s, __fmul_rn(v[c], v[c]));
  sqb[i] = s;
#pragma unroll
  for (int c = 0; c < 6; ++c) x0nc[(size_t)i * 6 + c] = v[c];
  size_t base = (size_t)i * 32;
#pragma unroll
  for (int c = 0; c < 32; ++c) {
    float xv = (c < 6) ? v[c] : 0.f;
    ushort h, m, l;
    split3(xv, h, m, l);
    xh[base + c] = h; xm[base + c] = m; xlo[base + c] = l;
  }
}

// ---------- fused BN+LReLU apply + split prep (r7-proven) ----------
__global__ __launch_bounds__(256) void k_applyprep(float* __restrict__ xio, const double* __restrict__ st,
                                                   const float* __restrict__ g, const float* __restrict__ bb,
                                                   ushort* __restrict__ xh, ushort* __restrict__ xm,
                                                   ushort* __restrict__ xlo, float* __restrict__ sqb) {
  __shared__ float sa[64], sd[64];
  const int tid = threadIdx.x;
  if (tid < 64) {
    constexpr double invM = 1.0 / (double)(BB * NN * KK);
    double sm = st[tid] * invM;
    double ad = (double)g[tid] / sqrt(st[64 + tid] * invM - sm * sm + EPSD);
    sa[tid] = (float)ad;
    sd[tid] = (float)((double)bb[tid] - sm * ad);
  }
  __syncthreads();
  int i = blockIdx.x * 256 + tid;
  float* src = xio + (size_t)i * 64;
  float v[64];
#pragma unroll
  for (int c4 = 0; c4 < 16; ++c4) {
    float4 t = *reinterpret_cast<const float4*>(src + 4 * c4);
    v[4 * c4 + 0] = t.x; v[4 * c4 + 1] = t.y; v[4 * c4 + 2] = t.z; v[4 * c4 + 3] = t.w;
  }
#pragma unroll
  for (int c = 0; c < 64; ++c) v[c] = lrelu(fmaf(sa[c], v[c], sd[c]));
  float s = 0.f;
#pragma unroll
  for (int c = 0; c < 64; ++c) s = __fadd_rn(s, __fmul_rn(v[c], v[c]));
  sqb[i] = s;
#pragma unroll
  for (int c4 = 0; c4 < 16; ++c4) {
    float4 t;
    t.x = v[4 * c4 + 0]; t.y = v[4 * c4 + 1]; t.z = v[4 * c4 + 2]; t.w = v[4 * c4 + 3];
    *reinterpret_cast<float4*>(src + 4 * c4) = t;
  }
  size_t base = (size_t)i * 64;
#pragma unroll
  for (int c = 0; c < 64; ++c) {
    ushort h, m, l;
    split3(v[c], h, m, l);
    xh[base + c] = h; xm[base + c] = m; xlo[base + c] = l;
  }
}

// ---------- MFMA Gram (r5-proven): S[bl][i][j] = (2*<x_i,x_j> - sq_i) - sq_j ----------
template <int CP>
__global__ __launch_bounds__(256) void k_gram(const ushort* __restrict__ xh, const ushort* __restrict__ xm,
                                              const ushort* __restrict__ xlo, const float* __restrict__ sqb,
                                              float* __restrict__ S, int b0) {
  constexpr int KS = CP / 32;
  const int bl = blockIdx.z, b = b0 + bl;
  const int r0 = blockIdx.x * 32;
  const int cc0 = blockIdx.y * 32;
  const int tid = threadIdx.x, w = tid >> 6, l = tid & 63;
  const int rt = w & 1;
  const size_t xb = (size_t)b * NN * CP;
  const int ko = (l >> 4) * 8;

  short8 Ah[KS], Am[KS], Al[KS];
  const int ar = r0 + rt * 16 + (l & 15);
#pragma unroll
  for (int ks = 0; ks < KS; ++ks) {
    size_t o = xb + (size_t)ar * CP + ks * 32 + ko;
    Ah[ks] = *reinterpret_cast<const short8*>(xh + o);
    Am[ks] = *reinterpret_cast<const short8*>(xm + o);
    Al[ks] = *reinterpret_cast<const short8*>(xlo + o);
  }
  float sqi[4];
  const int rr = r0 + rt * 16 + (l >> 4) * 4;
#pragma unroll
  for (int q = 0; q < 4; ++q) sqi[q] = sqb[b * NN + rr + q];
  const size_t Sbase = ((size_t)bl * NN + rr) * NN;

  int ct = cc0 + (w >> 1);
  short8 Bh[KS], Bm[KS], Bl[KS], Ch[KS], Cm[KS], Cl[KS];
#pragma unroll
  for (int ks = 0; ks < KS; ++ks) {
    size_t o = xb + (size_t)(ct * 16 + (l & 15)) * CP + ks * 32 + ko;
    Bh[ks] = *reinterpret_cast<const short8*>(xh + o);
    Bm[ks] = *reinterpret_cast<const short8*>(xm + o);
    Bl[ks] = *reinterpret_cast<const short8*>(xlo + o);
  }
  for (int t = 0; t < 16; ++t) {
    int nct = ct + 2;
    if (t < 15) {
#pragma unroll
      for (int ks = 0; ks < KS; ++ks) {
        size_t o = xb + (size_t)(nct * 16 + (l & 15)) * CP + ks * 32 + ko;
        Ch[ks] = *reinterpret_cast<const short8*>(xh + o);
        Cm[ks] = *reinterpret_cast<const short8*>(xm + o);
        Cl[ks] = *reinterpret_cast<const short8*>(xlo + o);
      }
    }
    f32x4 acc = {0.f, 0.f, 0.f, 0.f};
#pragma unroll
    for (int ks = 0; ks < KS; ++ks) {
      acc = __builtin_amdgcn_mfma_f32_16x16x32_bf16(Am[ks], Bm[ks], acc, 0, 0, 0);
      acc = __builtin_amdgcn_mfma_f32_16x16x32_bf16(Ah[ks], Bl[ks], acc, 0, 0, 0);
      acc = __builtin_amdgcn_mfma_f32_16x16x32_bf16(Al[ks], Bh[ks], acc, 0, 0, 0);
      acc = __builtin_amdgcn_mfma_f32_16x16x32_bf16(Ah[ks], Bm[ks], acc, 0, 0, 0);
      acc = __builtin_amdgcn_mfma_f32_16x16x32_bf16(Am[ks], Bh[ks], acc, 0, 0, 0);
      acc = __builtin_amdgcn_mfma_f32_16x16x32_bf16(Ah[ks], Bh[ks], acc, 0, 0, 0);
    }
    int col = ct * 16 + (l & 15);
    float sqj = sqb[b * NN + col];
#pragma unroll
    for (int q = 0; q < 4; ++q) {
      float sc = __fsub_rn(__fsub_rn(2.f * acc[q], sqi[q]), sqj);
      S[Sbase + (size_t)q * NN + col] = sc;
    }
#pragma unroll
    for (int ks = 0; ks < KS; ++ks) { Bh[ks] = Ch[ks]; Bm[ks] = Cm[ks]; Bl[ks] = Cl[ks]; }
    ct = nct;
  }
}

// ---------- tournament top-20 select (r5-proven): one wave per row ----------
__global__ __launch_bounds__(256) void k_select(const float* __restrict__ S, int* __restrict__ idxo, int b0) {
  const int bl = blockIdx.y, b = b0 + bl;
  const int wv = threadIdx.x >> 6, l = threadIdx.x & 63;
  const int row = blockIdx.x * 4 + wv;
  __shared__ float sr[4][2048];
  __shared__ int oid[4][20];
  char* base = reinterpret_cast<char*>(&sr[wv][0]);
  const float* Sp = S + ((size_t)bl * NN + row) * NN;
#pragma unroll
  for (int e = 0; e < 8; ++e) {
    float4 v = *reinterpret_cast<const float4*>(Sp + e * 256 + l * 4);
    int c = e * 64 + l;
    c ^= (c >> 3) & 7;
    *reinterpret_cast<float4*>(base + (c << 4)) = v;
  }
  float v0 = EMPTYV, v1 = EMPTYV;
  int i0 = -1, i1 = -1;
#pragma unroll
  for (int e = 0; e < 8; ++e) {
    int c = l * 8 + e;
    c ^= (c >> 3) & 7;
    float4 v = *reinterpret_cast<const float4*>(base + (c << 4));
    int jb = l * 32 + e * 4;
    float va[4] = {v.x, v.y, v.z, v.w};
#pragma unroll
    for (int q = 0; q < 4; ++q) {
      float vv = va[q];
      int jj = jb + q;
      if (vv > v0) { v1 = v0; i1 = i0; v0 = vv; i0 = jj; }
      else if (vv > v1) { v1 = vv; i1 = jj; }
    }
  }
  for (int e = 0; e < KK; ++e) {
    float m = v0;
#pragma unroll
    for (int d = 1; d < 64; d <<= 1) m = fmaxf(m, __shfl_xor(m, d));
    unsigned long long msk = __ballot(v0 == m);
    int wl = __ffsll((unsigned long long)msk) - 1;
    if (l == wl) {
      oid[wv][e] = i0;
      int j = i0;
      int cc = j >> 2;
      int cs = cc ^ ((cc >> 3) & 7);
      *reinterpret_cast<float*>(base + (cs << 4) + ((j & 3) << 2)) = NEG;
      v0 = v1; i0 = i1; v1 = EMPTYV; i1 = -1;
      if (v0 <= EMPTYV) {
        v0 = EMPTYV; v1 = EMPTYV; i0 = -1; i1 = -1;
#pragma unroll
        for (int e2 = 0; e2 < 8; ++e2) {
          int c = l * 8 + e2;
          c ^= (c >> 3) & 7;
          float4 v = *reinterpret_cast<const float4*>(base + (c << 4));
          int jb = l * 32 + e2 * 4;
          float va[4] = {v.x, v.y, v.z, v.w};
#pragma unroll
          for (int q = 0; q < 4; ++q) {
            float vv = va[q];
            int jj = jb + q;
            if (vv > v0) { v1 = v0; i1 = i0; v0 = vv; i0 = jj; }
            else if (vv > v1) { v1 = vv; i1 = jj; }
          }
        }
      }
    }
  }
  if (l < KK) idxo[((size_t)b * NN + row) * KK + l] = oid[wv][l];
}

// ---------- u = (W1-W2)x, v = W2 x ----------
template <int C>
__global__ __launch_bounds__(256) void k_uv(const float* __restrict__ xin, const float* __restrict__ w,
                                            float* __restrict__ u, float* __restrict__ v) {
  const int b = blockIdx.y, n0 = blockIdx.x * 4;
  const int tid = threadIdx.x, o = tid & 63, nn = tid >> 6;
  __shared__ float wl[64][2 * C + 1];
  __shared__ float xl[4][C];
  for (int t = tid; t < 64 * 2 * C; t += 256) wl[t / (2 * C)][t % (2 * C)] = w[t];
  for (int t = tid; t < 4 * C; t += 256) xl[t / C][t % C] = xin[((size_t)b * NN + n0 + t / C) * C + t % C];
  __syncthreads();
  float s1 = 0.f, s2 = 0.f;
#pragma unroll
  for (int c = 0; c < C; ++c) {
    float xv = xl[nn][c];
    s1 = fmaf(wl[o][c], xv, s1);
    s2 = fmaf(wl[o][C + c], xv, s2);
  }
  size_t i = ((size_t)b * NN + n0 + nn) * 64 + o;
  u[i] = s1 - s2;
  v[i] = s2;
}

// ---------- stats of t1 = u[n] + v[j] ----------
__global__ __launch_bounds__(256) void k_passA(const float* __restrict__ u, const float* __restrict__ v,
                                               const int* __restrict__ idx, double* __restrict__ st) {
  const int b = blockIdx.y, n0 = blockIdx.x * 16;
  const int tid = threadIdx.x, c = tid & 63, nw = tid >> 6;
  double s = 0.0, ss = 0.0;
  for (int nn = nw; nn < 16; nn += 4) {
    size_t nb = (size_t)b * NN + n0 + nn;
    float uu = u[nb * 64 + c];
    const int* ip = idx + nb * KK;
#pragma unroll
    for (int k = 0; k < KK; ++k) {
      float val = uu + v[((size_t)b * NN + ip[k]) * 64 + c];
      double dv = (double)val;
      s += dv; ss = fma(dv, dv, ss);
    }
  }
  __shared__ double red[2][4][64];
  red[0][nw][c] = s; red[1][nw][c] = ss;
  __syncthreads();
  if (tid < 64) {
    double S = red[0][0][tid] + red[0][1][tid] + red[0][2][tid] + red[0][3][tid];
    double SS = red[1][0][tid] + red[1][1][tid] + red[1][2][tid] + red[1][3][tid];
    atomicAdd(&st[tid], S);
    atomicAdd(&st[64 + tid], SS);
  }
}

// ---------- single-stage: stats + max over k ----------
__global__ __launch_bounds__(256) void k_passAmax(const float* __restrict__ u, const float* __restrict__ v,
                                                  const int* __restrict__ idx, float* __restrict__ xout,
                                                  double* __restrict__ st) {
  const int b = blockIdx.y, n0 = blockIdx.x * 16;
  const int tid = threadIdx.x, c = tid & 63, nw = tid >> 6;
  double s = 0.0, ss = 0.0;
  for (int nn = nw; nn < 16; nn += 4) {
    size_t nb = (size_t)b * NN + n0 + nn;
    float uu = u[nb * 64 + c];
    const int* ip = idx + nb * KK;
    float mx = NEG;
#pragma unroll
    for (int k = 0; k < KK; ++k) {
      float val = uu + v[((size_t)b * NN + ip[k]) * 64 + c];
      mx = fmaxf(mx, val);
      double dv = (double)val;
      s += dv; ss = fma(dv, dv, ss);
    }
    xout[nb * 64 + c] = mx;
  }
  __shared__ double red[2][4][64];
  red[0][nw][c] = s; red[1][nw][c] = ss;
  __syncthreads();
  if (tid < 64) {
    double S = red[0][0][tid] + red[0][1][tid] + red[0][2][tid] + red[0][3][tid];
    double SS = red[1][0][tid] + red[1][1][tid] + red[1][2][tid] + red[1][3][tid];
    atomicAdd(&st[tid], S);
    atomicAdd(&st[64 + tid], SS);
  }
}

// ---------- multi-stage conv2 (r5-proven, 110 µs) ----------
__global__ __launch_bounds__(256) void k_passB(const float* __restrict__ u, const float* __restrict__ v,
                                               const int* __restrict__ idx, const double* __restrict__ st1,
                                               const float* __restrict__ g1, const float* __restrict__ b1,
                                               const float* __restrict__ w2, float* __restrict__ xout,
                                               double* __restrict__ st2) {
  const int b = blockIdx.y, n0 = blockIdx.x * 8;
  const int tid = threadIdx.x, lane = tid & 63, wv = tid >> 6;
  __shared__ __align__(16) float act[160][64];
  constexpr double invM = 1.0 / (double)(BB * NN * KK);
  double sm = st1[lane] * invM;
  double ad = (double)g1[lane] / sqrt(st1[64 + lane] * invM - sm * sm + EPSD);
  float a = (float)ad;
  float d = (float)((double)b1[lane] - sm * ad);
  float wr[64];
#pragma unroll
  for (int c4 = 0; c4 < 16; ++c4) {
    float4 t4 = *reinterpret_cast<const float4*>(w2 + (size_t)lane * 64 + 4 * c4);
    wr[4 * c4 + 0] = t4.x; wr[4 * c4 + 1] = t4.y; wr[4 * c4 + 2] = t4.z; wr[4 * c4 + 3] = t4.w;
  }
  for (int p = wv; p < 160; p += 4) {
    int nn = p / 20, k = p - nn * 20;
    size_t nb = (size_t)b * NN + n0 + nn;
    int j = idx[nb * KK + k];
    float val = u[nb * 64 + lane] + v[((size_t)b * NN + j) * 64 + lane];
    act[p][lane] = lrelu(fmaf(a, val, d));
  }
  __syncthreads();
  double s2 = 0.0, ss2 = 0.0;
#pragma unroll
  for (int q = 0; q < 2; ++q) {
    int nl = 2 * wv + q;
    float mx = NEG;
#pragma unroll 4
    for (int k = 0; k < KK; ++k) {
      const float* ap = &act[nl * 20 + k][0];
      float a0 = 0.f, a1 = 0.f, a2 = 0.f, a3 = 0.f;
#pragma unroll
      for (int c4 = 0; c4 < 16; ++c4) {
        float4 v4 = *reinterpret_cast<const float4*>(ap + 4 * c4);
        a0 = fmaf(wr[4 * c4 + 0], v4.x, a0);
        a1 = fmaf(wr[4 * c4 + 1], v4.y, a1);
        a2 = fmaf(wr[4 * c4 + 2], v4.z, a2);
        a3 = fmaf(wr[4 * c4 + 3], v4.w, a3);
      }
      float t2v = (a0 + a1) + (a2 + a3);
      mx = fmaxf(mx, t2v);
      double dv = (double)t2v;
      s2 += dv; ss2 = fma(dv, dv, ss2);
    }
    xout[((size_t)b * NN + n0 + nl) * 64 + lane] = mx;
  }
  __syncthreads();
  double* red = reinterpret_cast<double*>(&act[0][0]);
  red[wv * 64 + lane] = s2;
  red[256 + wv * 64 + lane] = ss2;
  __syncthreads();
  if (tid < 64) {
    double S = red[tid] + red[64 + tid] + red[128 + tid] + red[192 + tid];
    double SS = red[256 + tid] + red[320 + tid] + red[384 + tid] + red[448 + tid];
    atomicAdd(&st2[tid], S);
    atomicAdd(&st2[64 + tid], SS);
  }
}

// ---------- in-place BN+LReLU (stage 3 output) ----------
__global__ __launch_bounds__(256) void k_apply(float* __restrict__ xio, const double* __restrict__ st,
                                               const float* __restrict__ g, const float* __restrict__ bb,
                                               double invM) {
  const int b = blockIdx.y, n0 = blockIdx.x * 4;
  const int tid = threadIdx.x, c = tid & 63, nn = tid >> 6;
  double sm = st[c] * invM;
  double ad = (double)g[c] / sqrt(st[64 + c] * invM - sm * sm + EPSD);
  float a = (float)ad;
  float d = (float)((double)bb[c] - sm * ad);
  size_t i = ((size_t)b * NN + n0 + nn) * 64 + c;
  xio[i] = lrelu(fmaf(a, xio[i], d));
}

// ---------- wt transpose ----------
__global__ __launch_bounds__(256) void k_wtT(const float* __restrict__ wt, float* __restrict__ wtT) {
  int i = blockIdx.x * 256 + threadIdx.x;
  if (i < 128 * 256) { int o = i >> 8, c = i & 255; wtT[c * 128 + o] = wt[i]; }
}

// ---------- tail GEMM ----------
__global__ __launch_bounds__(256) void k_tail(const float* __restrict__ x1, const float* __restrict__ x2,
                                              const float* __restrict__ x3, const float* __restrict__ x4,
                                              const float* __restrict__ wtT, float* __restrict__ tt) {
  const int b = blockIdx.y, n0 = blockIdx.x * 16;
  const int tid = threadIdx.x, og = tid & 31, nt = tid >> 5;
  __shared__ float xc[256][20];
  const float* xs[4] = {x1, x2, x3, x4};
  for (int t = tid; t < 4096; t += 256) {
    int n = t >> 8, c = t & 255;
    xc[c][n] = xs[c >> 6][((size_t)b * NN + n0 + n) * 64 + (c & 63)];
  }
  __syncthreads();
  float acc[4][2];
#pragma unroll
  for (int r = 0; r < 4; ++r) { acc[r][0] = 0.f; acc[r][1] = 0.f; }
#pragma unroll 4
  for (int c = 0; c < 256; ++c) {
    float4 wv = *reinterpret_cast<const float4*>(&wtT[(size_t)c * 128 + 4 * og]);
    float xc0 = xc[c][2 * nt], xc1 = xc[c][2 * nt + 1];
    acc[0][0] = fmaf(wv.x, xc0, acc[0][0]); acc[0][1] = fmaf(wv.x, xc1, acc[0][1]);
    acc[1][0] = fmaf(wv.y, xc0, acc[1][0]); acc[1][1] = fmaf(wv.y, xc1, acc[1][1]);
    acc[2][0] = fmaf(wv.z, xc0, acc[2][0]); acc[2][1] = fmaf(wv.z, xc1, acc[2][1]);
    acc[3][0] = fmaf(wv.w, xc0, acc[3][0]); acc[3][1] = fmaf(wv.w, xc1, acc[3][1]);
  }
#pragma unroll
  for (int q = 0; q < 2; ++q) {
    float4 o4;
    o4.x = acc[0][q]; o4.y = acc[1][q]; o4.z = acc[2][q]; o4.w = acc[3][q];
    *reinterpret_cast<float4*>(&tt[((size_t)b * NN + n0 + 2 * nt + q) * 128 + 4 * og]) = o4;
  }
}

// ---------- tail stats ----------
__global__ __launch_bounds__(256) void k_tailstats(const float* __restrict__ tt, double* __restrict__ st) {
  const int tid = threadIdx.x, c = tid & 127, h = tid >> 7;
  const int r0 = blockIdx.x * 32;
  double s = 0.0, ss = 0.0;
  for (int rr = h; rr < 32; rr += 2) {
    double val = (double)tt[(size_t)(r0 + rr) * 128 + c];
    s += val; ss = fma(val, val, ss);
  }
  __shared__ double red[2][2][128];
  red[0][h][c] = s; red[1][h][c] = ss;
  __syncthreads();
  if (tid < 128) {
    atomicAdd(&st[tid], red[0][0][tid] + red[0][1][tid]);
    atomicAdd(&st[128 + tid], red[1][0][tid] + red[1][1][tid]);
  }
}

// ---------- tail BN+LReLU + transpose ----------
__global__ __launch_bounds__(256) void k_tailapply(const float* __restrict__ tt, const double* __restrict__ st,
                                                   const float* __restrict__ g, const float* __restrict__ bb,
                                                   float* __restrict__ out) {
  const int b = blockIdx.y, n0 = blockIdx.x * 64;
  const int tid = threadIdx.x;
  __shared__ float tl[128][65];
  constexpr double invM = 1.0 / (double)(BB * NN);
  {
    const int o = tid & 127, h = tid >> 7;
    double sm = st[o] * invM;
    double ad = (double)g[o] / sqrt(st[128 + o] * invM - sm * sm + EPSD);
    float a = (float)ad;
    float d = (float)((double)bb[o] - sm * ad);
    for (int nn2 = h; nn2 < 64; nn2 += 2) {
      float val = tt[((size_t)b * NN + n0 + nn2) * 128 + o];
      tl[o][nn2] = lrelu(fmaf(a, val, d));
    }
  }
  __syncthreads();
  {
    const int nl = tid & 63, ow = tid >> 6;
    for (int o = ow; o < 128; o += 4)
      out[((size_t)b * 128 + o) * NN + n0 + nl] = tl[o][nl];
  }
}

extern "C" void kernel_launch(void* const* d_in, const int* in_sizes, int n_in,
                              void* d_out, int out_size, void* d_ws, size_t ws_size,
                              hipStream_t stream) {
  const float* x = (const float*)d_in[0];
  const float* w0a = (const float*)d_in[1];
  const float* g0a = (const float*)d_in[2];
  const float* b0a = (const float*)d_in[3];
  const float* w0b = (const float*)d_in[4];
  const float* g0b = (const float*)d_in[5];
  const float* b0b = (const float*)d_in[6];
  const float* w1a = (const float*)d_in[7];
  const float* g1a = (const float*)d_in[8];
  const float* b1a = (const float*)d_in[9];
  const float* w1b = (const float*)d_in[10];
  const float* g1b = (const float*)d_in[11];
  const float* b1b = (const float*)d_in[12];
  const float* w2 = (const float*)d_in[13];
  const float* g2 = (const float*)d_in[14];
  const float* b2 = (const float*)d_in[15];
  const float* w3 = (const float*)d_in[16];
  const float* g3 = (const float*)d_in[17];
  const float* b3 = (const float*)d_in[18];
  const float* wt = (const float*)d_in[19];
  const float* gt = (const float*)d_in[20];
  const float* bt = (const float*)d_in[21];
  float* out = (float*)d_out;

  char* p = (char*)d_ws;
  double* stA = (double*)p; p += 2048;
  double* stB = (double*)p; p += 2048;
  double* stT = (double*)p; p += 2048;
  ushort* xh = (ushort*)p; p += (size_t)BB * NN * 64 * 2;
  ushort* xm = (ushort*)p; p += (size_t)BB * NN * 64 * 2;
  ushort* xlo = (ushort*)p; p += (size_t)BB * NN * 64 * 2;
  float* sqb = (float*)p; p += (size_t)BB * NN * 4;
  float* x0nc = (float*)p; p += (size_t)BB * NN * 6 * 4;
  float* x1 = (float*)p; p += (size_t)BB * NN * 64 * 4;
  float* x2 = (float*)p; p += (size_t)BB * NN * 64 * 4;
  float* x3 = (float*)p; p += (size_t)BB * NN * 64 * 4;
  float* x4 = (float*)p; p += (size_t)BB * NN * 64 * 4;
  float* ub = (float*)p; p += (size_t)BB * NN * 64 * 4;
  float* vb = (float*)p; p += (size_t)BB * NN * 64 * 4;
  float* ttl = (float*)p; p += (size_t)BB * NN * 128 * 4;
  float* wtTb = (float*)p; p += 128 * 256 * 4;
  int* idx = (int*)p; p += (size_t)BB * NN * KK * 4;
  size_t base_bytes = (size_t)(p - (char*)d_ws);
  const size_t SBYTES = (size_t)NN * NN * 4;  // 16 MB per batch

  float* S;
  int bc;
  if (ws_size >= base_bytes + SBYTES) {
    S = (float*)(((uintptr_t)p + 255) & ~(uintptr_t)255);
    size_t avail = ws_size - ((char*)S - (char*)d_ws);
    bc = (int)(avail / SBYTES);
    if (bc > BB) bc = BB;
    if (bc < 1) { S = ub; bc = 1; }
  } else {
    S = ub;  // ub+vb+ttl region = exactly 16 MB, dead during kNN phase
    bc = 1;
  }

  constexpr double invMe = 1.0 / (double)(BB * NN * KK);
  dim3 blk(256);

  auto knn = [&](int stage) {
    for (int c = 0; c < BB; c += bc) {
      int nb = BB - c < bc ? BB - c : bc;
      if (stage == 0)
        k_gram<32><<<dim3(NN / 32, 4, nb), blk, 0, stream>>>(xh, xm, xlo, sqb, S, c);
      else
        k_gram<64><<<dim3(NN / 32, 4, nb), blk, 0, stream>>>(xh, xm, xlo, sqb, S, c);
      k_select<<<dim3(NN / 4, nb), blk, 0, stream>>>(S, idx, c);
    }
  };

  // stage 0 (multi, C=6)
  k_prep0<<<dim3(BB * NN / 256), blk, 0, stream>>>(x, x0nc, xh, xm, xlo, sqb);
  knn(0);
  k_uv<6><<<dim3(NN / 4, BB), blk, 0, stream>>>(x0nc, w0a, ub, vb);
  hipMemsetAsync(stA, 0, 4096, stream);  // stA+stB contiguous
  k_passA<<<dim3(NN / 16, BB), blk, 0, stream>>>(ub, vb, idx, stA);
  k_passB<<<dim3(NN / 8, BB), blk, 0, stream>>>(ub, vb, idx, stA, g0a, b0a, w0b, x1, stB);
  k_applyprep<<<dim3(BB * NN / 256), blk, 0, stream>>>(x1, stB, g0b, b0b, xh, xm, xlo, sqb);

  // stage 1 (multi, C=64)
  knn(1);
  k_uv<64><<<dim3(NN / 4, BB), blk, 0, stream>>>(x1, w1a, ub, vb);
  hipMemsetAsync(stA, 0, 4096, stream);
  k_passA<<<dim3(NN / 16, BB), blk, 0, stream>>>(ub, vb, idx, stA);
  k_passB<<<dim3(NN / 8, BB), blk, 0, stream>>>(ub, vb, idx, stA, g1a, b1a, w1b, x2, stB);
  k_applyprep<<<dim3(BB * NN / 256), blk, 0, stream>>>(x2, stB, g1b, b1b, xh, xm, xlo, sqb);

  // stage 2 (single)
  knn(2);
  k_uv<64><<<dim3(NN / 4, BB), blk, 0, stream>>>(x2, w2, ub, vb);
  hipMemsetAsync(stA, 0, 2048, stream);
  k_passAmax<<<dim3(NN / 16, BB), blk, 0, stream>>>(ub, vb, idx, x3, stA);
  k_applyprep<<<dim3(BB * NN / 256), blk, 0, stream>>>(x3, stA, g2, b2, xh, xm, xlo, sqb);

  // stage 3 (single)
  knn(3);
  k_uv<64><<<dim3(NN / 4, BB), blk, 0, stream>>>(x3, w3, ub, vb);
  hipMemsetAsync(stA, 0, 2048, stream);
  k_passAmax<<<dim3(NN / 16, BB), blk, 0, stream>>>(ub, vb, idx, x4, stA);
  k_apply<<<dim3(NN / 4, BB), blk, 0, stream>>>(x4, stA, g3, b3, invMe);

  // tail
  k_wtT<<<dim3(128), blk, 0, stream>>>(wt, wtTb);
  k_tail<<<dim3(NN / 16, BB), blk, 0, stream>>>(x1, x2, x3, x4, wtTb, ttl);
  hipMemsetAsync(stT, 0, 2048, stream);
  k_tailstats<<<dim3(512), blk, 0, stream>>>(ttl, stT);
  k_tailapply<<<dim3(NN / 64, BB), blk, 0, stream>>>(ttl, stT, gt, bt, out);
}